// Round 16
// baseline (30714.734 us; speedup 1.0000x reference)
//
#include <hip/hip_runtime.h>
#include <hip/hip_fp16.h>

#define HF 192
#define BM 64
#define BKC 32

static inline int divup(int a, int b){ return (a+b-1)/b; }
static inline int imin(int a, int b){ return a < b ? a : b; }

// ---- static device workspace, 131,640,064 B (deploy-proven size) ----
#define G_WS_BYTES 131640064ull
__device__ __align__(256) char g_ws[G_WS_BYTES];

// stages 1/2 (naive fp32, n <= 40000):
#define OFF_H32   0ull
#define OFF_T132  30720000ull
#define OFF_T232  61440000ull
#define OFF_CUR32 92160000ull
// stage 3 (fused fp16, n = 160000) aliases same region:
#define OFF_HH    0ull
#define OFF_T1H   61440000ull
// CSR / small buffers
#define OFF_DEG  122880000ull
#define OFF_RP   123520000ull
#define OFF_COL  124160032ull
#define OFF_NRM  128000032ull
#define OFF_O1F  128640032ull
#define OFF_U1F  128760032ull
#define OFF_O2F  129240032ull
#define OFF_U2F  129720032ull
#define OFF_X1N  OFF_T132
#define OFF_X2N  (OFF_T132 + 1920000ull)
#define OFF_X1F  OFF_T1H
#define OFF_X2F  (OFF_T1H + 1920000ull)

__device__ __forceinline__ float*  wsf(unsigned long long o){ return (float*) (g_ws + o); }
__device__ __forceinline__ int*    wsi(unsigned long long o){ return (int*)   (g_ws + o); }
__device__ __forceinline__ __half* wsh(unsigned long long o){ return (__half*)(g_ws + o); }

// ---------------- utility ----------------
__global__ void k_zero(unsigned long long off, int n) {
  int i = blockIdx.x*blockDim.x + threadIdx.x;
  if (i < n) wsi(off)[i] = 0;
}
__global__ void k_copyi(unsigned long long aOff, unsigned long long bOff, int n) {
  int i = blockIdx.x*blockDim.x + threadIdx.x;
  if (i < n) wsi(bOff)[i] = wsi(aOff)[i];
}

// ---------------- CSR build ----------------
__global__ void k_count_direct(const int* __restrict__ dst, int E) {
  int* deg = wsi(OFF_DEG);
  int e = blockIdx.x*blockDim.x + threadIdx.x;
  if (e < E) atomicAdd(&deg[dst[e]], 1);
}
__global__ void k_count_bidir(const int* __restrict__ edge, int E) {
  int* deg = wsi(OFF_DEG);
  int e = blockIdx.x*blockDim.x + threadIdx.x;
  if (e < E) {
    atomicAdd(&deg[edge[2*e+1]], 1);
    atomicAdd(&deg[edge[2*e  ]], 1);
  }
}
__global__ void k_norm(int n) {
  const int* deg = wsi(OFF_DEG);
  float* nrm = wsf(OFF_NRM);
  int i = blockIdx.x*blockDim.x + threadIdx.x;
  if (i < n) {
    int d = deg[i]; if (d < 1) d = 1;
    nrm[i] = rsqrtf((float)d);
  }
}
__global__ __launch_bounds__(1024) void k_exscan(int n) {
  const int* in = wsi(OFF_DEG);
  int* out = wsi(OFF_RP);
  __shared__ int sm[1024];
  int t = threadIdx.x;
  int carry = 0;
  for (int base = 0; base < n; base += 4096) {
    int idx = base + t*4;
    int v0 = (idx+0 < n) ? in[idx+0] : 0;
    int v1 = (idx+1 < n) ? in[idx+1] : 0;
    int v2 = (idx+2 < n) ? in[idx+2] : 0;
    int v3 = (idx+3 < n) ? in[idx+3] : 0;
    int s = v0+v1+v2+v3;
    sm[t] = s;
    __syncthreads();
    for (int off = 1; off < 1024; off <<= 1) {
      int u = (t >= off) ? sm[t-off] : 0;
      __syncthreads();
      sm[t] += u;
      __syncthreads();
    }
    int excl = carry + sm[t] - s;
    if (idx   < n) out[idx]   = excl;
    if (idx+1 < n) out[idx+1] = excl + v0;
    if (idx+2 < n) out[idx+2] = excl + v0+v1;
    if (idx+3 < n) out[idx+3] = excl + v0+v1+v2;
    carry += sm[1023];
    __syncthreads();
  }
  if (t == 0) out[n] = carry;
}
__global__ void k_fill_direct(const int* __restrict__ src, const int* __restrict__ dst, int E) {
  int* cur = wsi(OFF_DEG);
  int* col = wsi(OFF_COL);
  int e = blockIdx.x*blockDim.x + threadIdx.x;
  if (e < E) {
    int p = atomicAdd(&cur[dst[e]], 1);
    col[p] = src[e];
  }
}
__global__ void k_fill_bidir(const int* __restrict__ edge, int E) {
  int* cur = wsi(OFF_DEG);
  int* col = wsi(OFF_COL);
  int e = blockIdx.x*blockDim.x + threadIdx.x;
  if (e < E) {
    int u = edge[2*e], v = edge[2*e+1];
    int p = atomicAdd(&cur[v], 1); col[p] = u;
    int q = atomicAdd(&cur[u], 1); col[q] = v;
  }
}

// ---------------- propagation dim-3 (f32) ----------------
__global__ void k_spmm3(const float* __restrict__ Xext, unsigned long long Xoff,
                        unsigned long long Yoff, int n) {
  const float* X = Xext ? Xext : wsf(Xoff);
  float* Y = wsf(Yoff);
  const int* rowptr = wsi(OFF_RP);
  const int* col = wsi(OFF_COL);
  const float* nrm = wsf(OFF_NRM);
  int row = blockIdx.x*blockDim.x + threadIdx.x;
  if (row >= n) return;
  int s = rowptr[row], e = rowptr[row+1];
  float a0=0.f, a1=0.f, a2=0.f;
  for (int i = s; i < e; ++i) {
    int c = col[i]; float v = nrm[c];
    a0 = fmaf(v, X[c*3+0], a0);
    a1 = fmaf(v, X[c*3+1], a1);
    a2 = fmaf(v, X[c*3+2], a2);
  }
  float nm = nrm[row];
  Y[row*3+0] = a0*nm; Y[row*3+1] = a1*nm; Y[row*3+2] = a2*nm;
}

// ======================= NAIVE fp32 path (stages 1 & 2) =======================
__global__ void k_nspmm(unsigned long long Xoff, unsigned long long Yoff, int n) {
  const float* __restrict__ X = wsf(Xoff);
  float* __restrict__ Y = wsf(Yoff);
  const int* rowptr = wsi(OFF_RP);
  const int* col = wsi(OFF_COL);
  const float* nrm = wsf(OFF_NRM);
  int idx = blockIdx.x*blockDim.x + threadIdx.x;
  if (idx >= n*HF) return;
  int row = idx / HF, f = idx - row*HF;
  int s = rowptr[row], e = rowptr[row+1];
  float acc = 0.f;
  for (int i = s; i < e; ++i) {
    int c = col[i];
    acc = fmaf(nrm[c], X[(size_t)c*HF + f], acc);
  }
  Y[idx] = acc * nrm[row];
}
__global__ void k_nfirst(const float* __restrict__ xext, unsigned long long xOff,
                         const float* __restrict__ W, const float* __restrict__ b, int n) {
  const float* x  = xext ? xext : wsf(xOff);
  const float* x1 = wsf(OFF_X1N);
  const float* x2 = wsf(OFF_X2N);
  float* H = wsf(OFF_H32);
  int idx = blockIdx.x*blockDim.x + threadIdx.x;
  if (idx >= n*HF) return;
  int row = idx / HF, c = idx - row*HF;
  float acc = b[c];
  #pragma unroll
  for (int k = 0; k < 3; ++k) acc = fmaf(x [row*3+k], W[(0+k)*HF + c], acc);
  #pragma unroll
  for (int k = 0; k < 3; ++k) acc = fmaf(x1[row*3+k], W[(3+k)*HF + c], acc);
  #pragma unroll
  for (int k = 0; k < 3; ++k) acc = fmaf(x2[row*3+k], W[(6+k)*HF + c], acc);
  H[idx] = fmaxf(acc, 0.f);
}
__global__ void k_ngemm(const float* __restrict__ W, const float* __restrict__ b, int n) {
  const float* __restrict__ H  = wsf(OFF_H32);
  const float* __restrict__ T1 = wsf(OFF_T132);
  const float* __restrict__ T2 = wsf(OFF_T232);
  float* __restrict__ CUR = wsf(OFF_CUR32);
  int idx = blockIdx.x*blockDim.x + threadIdx.x;
  if (idx >= n*HF) return;
  int row = idx / HF, c = idx - row*HF;
  float acc = b[c];
  const float* xh = &H [(size_t)row*HF];
  const float* x1 = &T1[(size_t)row*HF];
  const float* x2 = &T2[(size_t)row*HF];
  for (int k = 0; k < HF; ++k) acc = fmaf(xh[k], W[(size_t)(      k)*HF + c], acc);
  for (int k = 0; k < HF; ++k) acc = fmaf(x1[k], W[(size_t)(HF  + k)*HF + c], acc);
  for (int k = 0; k < HF; ++k) acc = fmaf(x2[k], W[(size_t)(2*HF+ k)*HF + c], acc);
  CUR[idx] = acc;
}
__global__ void k_nupdate(int n, int residual) {
  float* __restrict__ H = wsf(OFF_H32);
  const float* __restrict__ CUR = wsf(OFF_CUR32);
  int idx = blockIdx.x*blockDim.x + threadIdx.x;
  if (idx >= n*HF) return;
  float cur = fmaxf(CUR[idx], 0.f);
  H[idx] = residual ? 0.5f*(H[idx] + cur) : cur;
}
__global__ void k_nlast(const float* __restrict__ W, const float* __restrict__ b,
                        float* __restrict__ outb, unsigned long long outfOff,
                        int hasOutf, int n) {
  int row = blockIdx.x*blockDim.x + threadIdx.x;
  if (row >= n) return;
  const float* H  = wsf(OFF_H32);
  const float* T1 = wsf(OFF_T132);
  const float* T2 = wsf(OFF_T232);
  float a0 = b[0], a1 = b[1], a2 = b[2];
  const float* x = &H[(size_t)row*HF];
  for (int k = 0; k < HF; ++k) {
    float v = x[k]; const float* w = &W[k*3];
    a0 = fmaf(v, w[0], a0); a1 = fmaf(v, w[1], a1); a2 = fmaf(v, w[2], a2);
  }
  x = &T1[(size_t)row*HF];
  for (int k = 0; k < HF; ++k) {
    float v = x[k]; const float* w = &W[(HF+k)*3];
    a0 = fmaf(v, w[0], a0); a1 = fmaf(v, w[1], a1); a2 = fmaf(v, w[2], a2);
  }
  x = &T2[(size_t)row*HF];
  for (int k = 0; k < HF; ++k) {
    float v = x[k]; const float* w = &W[(2*HF+k)*3];
    a0 = fmaf(v, w[0], a0); a1 = fmaf(v, w[1], a1); a2 = fmaf(v, w[2], a2);
  }
  outb[row*3+0] = a0;
  outb[row*3+1] = a1;
  outb[row*3+2] = a2;
  if (hasOutf) {
    float* outf = wsf(outfOff);
    outf[row*3+0] = a0; outf[row*3+1] = a1; outf[row*3+2] = a2;
  }
}

// ======================= FUSED fp16 path (stage 3) =======================
__global__ __launch_bounds__(192) void k_spmm192h(int n) {
  const __half* __restrict__ X = wsh(OFF_HH);
  __half* __restrict__ Y = wsh(OFF_T1H);
  const int* rowptr = wsi(OFF_RP);
  const int* col = wsi(OFF_COL);
  const float* nrm = wsf(OFF_NRM);
  int f = threadIdx.x;
  for (int row = blockIdx.x; row < n; row += gridDim.x) {
    int s = rowptr[row], e = rowptr[row+1];
    float acc = 0.f;
    for (int i = s; i < e; ++i) {
      int c = col[i];
      acc = fmaf(nrm[c], __half2float(X[(size_t)c*HF + f]), acc);
    }
    Y[(size_t)row*HF + f] = __float2half(acc * nrm[row]);
  }
}
__global__ void k_gemm_first(const float* __restrict__ xext, unsigned long long xOff,
                             const float* __restrict__ W, const float* __restrict__ b, int n) {
  const float* x  = xext ? xext : wsf(xOff);
  const float* x1 = wsf(OFF_X1F);
  const float* x2 = wsf(OFF_X2F);
  __half* H = wsh(OFF_HH);
  int idx = blockIdx.x*blockDim.x + threadIdx.x;
  if (idx >= n*HF) return;
  int row = idx / HF, c = idx - row*HF;
  float acc = b[c];
  #pragma unroll
  for (int k = 0; k < 3; ++k) acc = fmaf(x [row*3+k], W[(0+k)*HF + c], acc);
  #pragma unroll
  for (int k = 0; k < 3; ++k) acc = fmaf(x1[row*3+k], W[(3+k)*HF + c], acc);
  #pragma unroll
  for (int k = 0; k < 3; ++k) acc = fmaf(x2[row*3+k], W[(6+k)*HF + c], acc);
  H[idx] = __float2half(fmaxf(acc, 0.f));
}
__global__ __launch_bounds__(256) void k_gemm_mid(
    const float* __restrict__ W, const float* __restrict__ b, int n, int residual)
{
  __half* __restrict__ H = wsh(OFF_HH);
  const __half* __restrict__ T1 = wsh(OFF_T1H);
  const int* rowptr = wsi(OFF_RP);
  const int* col = wsi(OFF_COL);
  const float* nrm = wsf(OFF_NRM);
  __shared__ float Xst[BKC][68];
  __shared__ float Ws[BKC][HF];
  int t = threadIdx.x;
  int row0 = blockIdx.x * BM;
  int tx = t & 15, ty = t >> 4;
  int c0 = tx * 12;
  int r0 = ty * 4;
  float acc[4][12];
  #pragma unroll
  for (int i = 0; i < 4; ++i)
    #pragma unroll
    for (int j = 0; j < 12; ++j) acc[i][j] = 0.f;

  for (int part = 0; part < 3; ++part) {
    const float* Wp = W + (size_t)part * HF * HF;
    for (int kk = 0; kk < HF; kk += BKC) {
      __syncthreads();
      if (part < 2) {
        const __half* Xp = (part == 0) ? H : T1;
        for (int i = t; i < 512; i += 256) {
          int r  = i >> 3;
          int c4 = (i & 7) * 4;
          int gr = row0 + r;
          float v0=0.f, v1=0.f, v2=0.f, v3=0.f;
          if (gr < n) {
            const __half* hp = &Xp[(size_t)gr*HF + kk + c4];
            v0 = __half2float(hp[0]); v1 = __half2float(hp[1]);
            v2 = __half2float(hp[2]); v3 = __half2float(hp[3]);
          }
          Xst[c4+0][r] = v0; Xst[c4+1][r] = v1;
          Xst[c4+2][r] = v2; Xst[c4+3][r] = v3;
        }
      } else {
        for (int i = t; i < 512; i += 256) {
          int r  = i >> 3;
          int c4 = (i & 7) * 4;
          int gr = row0 + r;
          float v0=0.f, v1=0.f, v2=0.f, v3=0.f;
          if (gr < n) {
            int s = rowptr[gr], e = rowptr[gr+1];
            for (int j = s; j < e; ++j) {
              int c = col[j];
              float w = nrm[c];
              const __half* tp = &T1[(size_t)c*HF + kk + c4];
              v0 = fmaf(w, __half2float(tp[0]), v0);
              v1 = fmaf(w, __half2float(tp[1]), v1);
              v2 = fmaf(w, __half2float(tp[2]), v2);
              v3 = fmaf(w, __half2float(tp[3]), v3);
            }
            float nm = nrm[gr];
            v0 *= nm; v1 *= nm; v2 *= nm; v3 *= nm;
          }
          Xst[c4+0][r] = v0; Xst[c4+1][r] = v1;
          Xst[c4+2][r] = v2; Xst[c4+3][r] = v3;
        }
      }
      for (int i = t; i < 1536; i += 256) {
        int r  = i / 48;
        int c4 = (i % 48) * 4;
        *(float4*)&Ws[r][c4] = *(const float4*)&Wp[(size_t)(kk + r)*HF + c4];
      }
      __syncthreads();
      #pragma unroll
      for (int k = 0; k < BKC; ++k) {
        float4 a  = *(const float4*)&Xst[k][r0];
        float4 w0 = *(const float4*)&Ws[k][c0];
        float4 w1 = *(const float4*)&Ws[k][c0+4];
        float4 w2 = *(const float4*)&Ws[k][c0+8];
        float av[4]  = {a.x, a.y, a.z, a.w};
        float wv[12] = {w0.x,w0.y,w0.z,w0.w, w1.x,w1.y,w1.z,w1.w, w2.x,w2.y,w2.z,w2.w};
        #pragma unroll
        for (int i = 0; i < 4; ++i)
          #pragma unroll
          for (int j = 0; j < 12; ++j)
            acc[i][j] = fmaf(av[i], wv[j], acc[i][j]);
      }
    }
  }

  float bias[12];
  #pragma unroll
  for (int j = 0; j < 12; ++j) bias[j] = b[c0 + j];

  #pragma unroll
  for (int i = 0; i < 4; ++i) {
    int gr = row0 + r0 + i;
    if (gr < n) {
      size_t off = (size_t)gr*HF + c0;
      #pragma unroll
      for (int j = 0; j < 12; ++j) {
        float cur = fmaxf(acc[i][j] + bias[j], 0.f);
        float h = cur;
        if (residual) h = 0.5f*(__half2float(H[off + j]) + cur);
        H[off + j] = __float2half(h);
      }
    }
  }
}
__global__ void k_last(const float* __restrict__ W, const float* __restrict__ b,
                       float* __restrict__ outb, int n) {
  int row = blockIdx.x*blockDim.x + threadIdx.x;
  if (row >= n) return;
  const __half* H  = wsh(OFF_HH);
  const __half* T1 = wsh(OFF_T1H);
  const int* rowptr = wsi(OFF_RP);
  const int* col = wsi(OFF_COL);
  const float* nrm = wsf(OFF_NRM);
  float a0 = b[0], a1 = b[1], a2 = b[2];
  for (int k = 0; k < HF; ++k) {
    float v = __half2float(H[(size_t)row*HF + k]);
    const float* w = &W[k*3];
    a0 = fmaf(v, w[0], a0); a1 = fmaf(v, w[1], a1); a2 = fmaf(v, w[2], a2);
  }
  for (int k = 0; k < HF; ++k) {
    float v = __half2float(T1[(size_t)row*HF + k]);
    const float* w = &W[(HF+k)*3];
    a0 = fmaf(v, w[0], a0); a1 = fmaf(v, w[1], a1); a2 = fmaf(v, w[2], a2);
  }
  float nrow = nrm[row];
  int s = rowptr[row], e = rowptr[row+1];
  for (int i = s; i < e; ++i) {
    int c = col[i];
    float wn = nrow * nrm[c];
    float d0=0.f, d1=0.f, d2=0.f;
    const __half* tp = &T1[(size_t)c*HF];
    for (int k = 0; k < HF; ++k) {
      float v = __half2float(tp[k]);
      const float* w = &W[(2*HF+k)*3];
      d0 = fmaf(v, w[0], d0); d1 = fmaf(v, w[1], d1); d2 = fmaf(v, w[2], d2);
    }
    a0 = fmaf(wn, d0, a0); a1 = fmaf(wn, d1, a1); a2 = fmaf(wn, d2, a2);
  }
  outb[row*3+0] = a0;
  outb[row*3+1] = a1;
  outb[row*3+2] = a2;
}

// ---------------- unpool: ws f32 in -> ws f32 shadow + f32 out ----------------
__global__ void k_unpool(unsigned long long srcOff, const int* __restrict__ pidx,
                         unsigned long long dstfOff, float* __restrict__ dstb,
                         int n, int P) {
  const float* src = wsf(srcOff);
  float* dstf = wsf(dstfOff);
  int i = blockIdx.x*blockDim.x + threadIdx.x;
  if (i >= n + P) return;
  float v0, v1, v2;
  if (i < n) {
    v0 = src[i*3+0]; v1 = src[i*3+1]; v2 = src[i*3+2];
  } else {
    int a = pidx[(i-n)*2], c = pidx[(i-n)*2+1];
    v0 = 0.5f*(src[a*3+0] + src[c*3+0]);
    v1 = 0.5f*(src[a*3+1] + src[c*3+1]);
    v2 = 0.5f*(src[a*3+2] + src[c*3+2]);
  }
  dstf[i*3+0] = v0; dstf[i*3+1] = v1; dstf[i*3+2] = v2;
  dstb[i*3+0] = v0;
  dstb[i*3+1] = v1;
  dstb[i*3+2] = v2;
}

extern "C" void kernel_launch(void* const* d_in, const int* in_sizes, int n_in,
                              void* d_out, int out_size, void* d_ws, size_t ws_size,
                              hipStream_t stream) {
  (void)in_sizes; (void)n_in; (void)out_size; (void)d_ws; (void)ws_size;
  const float* features = (const float*)d_in[0];
  const int*  src0  = (const int*)d_in[1];
  const int*  dst0  = (const int*)d_in[2];
  const int*  pool0 = (const int*)d_in[3];
  const int*  edge0 = (const int*)d_in[4];
  const int*  pool1 = (const int*)d_in[5];
  const int*  edge1 = (const int*)d_in[6];
  const float* Wf = (const float*)d_in[7];
  const float* bfp = (const float*)d_in[8];
  const float* Wm = (const float*)d_in[9];
  const float* bm = (const float*)d_in[10];
  const float* Wl = (const float*)d_in[11];
  const float* bl = (const float*)d_in[12];
  float* out = (float*)d_out;   // reference outputs are float32 -> d_out is float*

  auto csr = [&](int n, const int* srcD, const int* dstD, int Edir,
                 const int* edgeB, int Eund) {
    k_zero<<<divup(n,256),256,0,stream>>>(OFF_DEG, n);
    if (srcD) k_count_direct<<<divup(Edir,256),256,0,stream>>>(dstD, Edir);
    else      k_count_bidir <<<divup(Eund,256),256,0,stream>>>(edgeB, Eund);
    k_norm<<<divup(n,256),256,0,stream>>>(n);
    k_exscan<<<1,1024,0,stream>>>(n);
    k_copyi<<<divup(n,256),256,0,stream>>>(OFF_RP, OFF_DEG, n);
    if (srcD) k_fill_direct<<<divup(Edir,256),256,0,stream>>>(srcD, dstD, Edir);
    else      k_fill_bidir <<<divup(Eund,256),256,0,stream>>>(edgeB, Eund);
  };

  auto stage_naive = [&](const float* xext, unsigned long long xOff, int n,
                         const int* srcD, const int* dstD, int Edir,
                         const int* edgeB, int Eund,
                         int s, float* outb, unsigned long long outfOff, int hasOutf) {
    csr(n, srcD, dstD, Edir, edgeB, Eund);
    k_spmm3<<<divup(n,256),256,0,stream>>>(xext, xOff, OFF_X1N, n);
    k_spmm3<<<divup(n,256),256,0,stream>>>(nullptr, OFF_X1N, OFF_X2N, n);
    k_nfirst<<<divup(n*HF,256),256,0,stream>>>(xext, xOff, Wf + (size_t)s*9*HF, bfp + s*HF, n);
    int gel = divup(n*HF,256);
    for (int it = 0; it < 12; ++it) {
      k_nspmm<<<gel,256,0,stream>>>(OFF_H32,  OFF_T132, n);
      k_nspmm<<<gel,256,0,stream>>>(OFF_T132, OFF_T232, n);
      k_ngemm<<<gel,256,0,stream>>>(Wm + ((size_t)s*12 + it)*576*HF, bm + (s*12+it)*HF, n);
      k_nupdate<<<gel,256,0,stream>>>(n, ((it+1)%2==0) ? 1 : 0);
    }
    k_nspmm<<<gel,256,0,stream>>>(OFF_H32,  OFF_T132, n);
    k_nspmm<<<gel,256,0,stream>>>(OFF_T132, OFF_T232, n);
    k_nlast<<<divup(n,256),256,0,stream>>>(Wl + (size_t)s*576*3, bl + s*3, outb, outfOff, hasOutf, n);
  };

  auto stage_fused = [&](unsigned long long xOff, int n,
                         const int* edgeB, int Eund,
                         int s, float* outb) {
    csr(n, nullptr, nullptr, 0, edgeB, Eund);
    k_spmm3<<<divup(n,256),256,0,stream>>>(nullptr, xOff, OFF_X1F, n);
    k_spmm3<<<divup(n,256),256,0,stream>>>(nullptr, OFF_X1F, OFF_X2F, n);
    k_gemm_first<<<divup(n*HF,256),256,0,stream>>>(nullptr, xOff, Wf + (size_t)s*9*HF, bfp + s*HF, n);
    int gprop = imin(n, 16384);
    for (int it = 0; it < 12; ++it) {
      k_spmm192h<<<gprop,192,0,stream>>>(n);
      k_gemm_mid<<<divup(n,BM),256,0,stream>>>(
          Wm + ((size_t)s*12 + it)*576*HF, bm + (s*12+it)*HF, n, ((it+1)%2==0) ? 1 : 0);
    }
    k_spmm192h<<<gprop,192,0,stream>>>(n);
    k_last<<<divup(n,256),256,0,stream>>>(Wl + (size_t)s*576*3, bl + s*3, outb, n);
  };

  // stage 1: n=10000, direct edges (naive fp32)
  stage_naive(features, 0ull, 10000, src0, dst0, 60000, nullptr, 0, 0,
              out + 0, OFF_O1F, 1);
  k_unpool<<<divup(40000,256),256,0,stream>>>(OFF_O1F, pool0, OFF_U1F, out + 630000, 10000, 30000);
  // stage 2: n=40000, bidir edge0 (naive fp32)
  stage_naive(nullptr, OFF_U1F, 40000, nullptr, nullptr, 0, edge0, 120000, 1,
              out + 30000, OFF_O2F, 1);
  k_unpool<<<divup(160000,256),256,0,stream>>>(OFF_O2F, pool1, OFF_U2F, out + 750000, 40000, 120000);
  // stage 3: n=160000, bidir edge1 (fused fp16)
  stage_fused(OFF_U2F, 160000, edge1, 480000, 2, out + 150000);
}

// Round 17
// 15855.659 us; speedup vs baseline: 1.9371x; 1.9371x over previous
//
#include <hip/hip_runtime.h>
#include <hip/hip_fp16.h>

#define HF 192
#define BM 64
#define BKC 32

static inline int divup(int a, int b){ return (a+b-1)/b; }

// ---- static device workspace, 131,640,064 B (deploy-proven size) ----
#define G_WS_BYTES 131640064ull
__device__ __align__(256) char g_ws[G_WS_BYTES];

// stages 1/2 (naive fp32, n <= 40000):
#define OFF_H32   0ull
#define OFF_T132  30720000ull
#define OFF_T232  61440000ull
#define OFF_CUR32 92160000ull
// stage 3 (fused fp16, n = 160000) aliases same region:
#define OFF_HH    0ull
#define OFF_T1H   61440000ull
// CSR / small buffers
#define OFF_DEG  122880000ull
#define OFF_RP   123520000ull
#define OFF_COL  124160032ull
#define OFF_NRM  128000032ull
#define OFF_O1F  128640032ull
#define OFF_U1F  128760032ull
#define OFF_O2F  129240032ull
#define OFF_U2F  129720032ull
#define OFF_X1N  OFF_T132
#define OFF_X2N  (OFF_T132 + 1920000ull)
#define OFF_X1F  OFF_T1H
#define OFF_X2F  (OFF_T1H + 1920000ull)

__device__ __forceinline__ float*  wsf(unsigned long long o){ return (float*) (g_ws + o); }
__device__ __forceinline__ int*    wsi(unsigned long long o){ return (int*)   (g_ws + o); }
__device__ __forceinline__ __half* wsh(unsigned long long o){ return (__half*)(g_ws + o); }

// ---------------- utility ----------------
__global__ void k_zero(unsigned long long off, int n) {
  int i = blockIdx.x*blockDim.x + threadIdx.x;
  if (i < n) wsi(off)[i] = 0;
}
__global__ void k_copyi(unsigned long long aOff, unsigned long long bOff, int n) {
  int i = blockIdx.x*blockDim.x + threadIdx.x;
  if (i < n) wsi(bOff)[i] = wsi(aOff)[i];
}

// ---------------- CSR build ----------------
__global__ void k_count_direct(const int* __restrict__ dst, int E) {
  int* deg = wsi(OFF_DEG);
  int e = blockIdx.x*blockDim.x + threadIdx.x;
  if (e < E) atomicAdd(&deg[dst[e]], 1);
}
__global__ void k_count_bidir(const int* __restrict__ edge, int E) {
  int* deg = wsi(OFF_DEG);
  int e = blockIdx.x*blockDim.x + threadIdx.x;
  if (e < E) {
    atomicAdd(&deg[edge[2*e+1]], 1);
    atomicAdd(&deg[edge[2*e  ]], 1);
  }
}
__global__ void k_norm(int n) {
  const int* deg = wsi(OFF_DEG);
  float* nrm = wsf(OFF_NRM);
  int i = blockIdx.x*blockDim.x + threadIdx.x;
  if (i < n) {
    int d = deg[i]; if (d < 1) d = 1;
    nrm[i] = rsqrtf((float)d);
  }
}
__global__ __launch_bounds__(1024) void k_exscan(int n) {
  const int* in = wsi(OFF_DEG);
  int* out = wsi(OFF_RP);
  __shared__ int sm[1024];
  int t = threadIdx.x;
  int carry = 0;
  for (int base = 0; base < n; base += 4096) {
    int idx = base + t*4;
    int v0 = (idx+0 < n) ? in[idx+0] : 0;
    int v1 = (idx+1 < n) ? in[idx+1] : 0;
    int v2 = (idx+2 < n) ? in[idx+2] : 0;
    int v3 = (idx+3 < n) ? in[idx+3] : 0;
    int s = v0+v1+v2+v3;
    sm[t] = s;
    __syncthreads();
    for (int off = 1; off < 1024; off <<= 1) {
      int u = (t >= off) ? sm[t-off] : 0;
      __syncthreads();
      sm[t] += u;
      __syncthreads();
    }
    int excl = carry + sm[t] - s;
    if (idx   < n) out[idx]   = excl;
    if (idx+1 < n) out[idx+1] = excl + v0;
    if (idx+2 < n) out[idx+2] = excl + v0+v1;
    if (idx+3 < n) out[idx+3] = excl + v0+v1+v2;
    carry += sm[1023];
    __syncthreads();
  }
  if (t == 0) out[n] = carry;
}
__global__ void k_fill_direct(const int* __restrict__ src, const int* __restrict__ dst, int E) {
  int* cur = wsi(OFF_DEG);
  int* col = wsi(OFF_COL);
  int e = blockIdx.x*blockDim.x + threadIdx.x;
  if (e < E) {
    int p = atomicAdd(&cur[dst[e]], 1);
    col[p] = src[e];
  }
}
__global__ void k_fill_bidir(const int* __restrict__ edge, int E) {
  int* cur = wsi(OFF_DEG);
  int* col = wsi(OFF_COL);
  int e = blockIdx.x*blockDim.x + threadIdx.x;
  if (e < E) {
    int u = edge[2*e], v = edge[2*e+1];
    int p = atomicAdd(&cur[v], 1); col[p] = u;
    int q = atomicAdd(&cur[u], 1); col[q] = v;
  }
}

// ---------------- propagation dim-3 (f32) ----------------
__global__ void k_spmm3(const float* __restrict__ Xext, unsigned long long Xoff,
                        unsigned long long Yoff, int n) {
  const float* X = Xext ? Xext : wsf(Xoff);
  float* Y = wsf(Yoff);
  const int* rowptr = wsi(OFF_RP);
  const int* col = wsi(OFF_COL);
  const float* nrm = wsf(OFF_NRM);
  int row = blockIdx.x*blockDim.x + threadIdx.x;
  if (row >= n) return;
  int s = rowptr[row], e = rowptr[row+1];
  float a0=0.f, a1=0.f, a2=0.f;
  for (int i = s; i < e; ++i) {
    int c = col[i]; float v = nrm[c];
    a0 = fmaf(v, X[c*3+0], a0);
    a1 = fmaf(v, X[c*3+1], a1);
    a2 = fmaf(v, X[c*3+2], a2);
  }
  float nm = nrm[row];
  Y[row*3+0] = a0*nm; Y[row*3+1] = a1*nm; Y[row*3+2] = a2*nm;
}

// ======================= fp32 path (stages 1 & 2) =======================
// SpMM fp32, float4 per thread: thread -> (row, f4), f4 in [0,48)
__global__ __launch_bounds__(192) void k_nspmm4(unsigned long long Xoff,
                                                unsigned long long Yoff, int n) {
  int gid = blockIdx.x*192 + threadIdx.x;
  if (gid >= n*48) return;
  int row = gid / 48, f4 = gid - row*48;
  const float4* __restrict__ X4 = (const float4*)wsf(Xoff);
  float4* __restrict__ Y4 = (float4*)wsf(Yoff);
  const int* rowptr = wsi(OFF_RP);
  const int* col = wsi(OFF_COL);
  const float* nrm = wsf(OFF_NRM);
  int s = rowptr[row], e = rowptr[row+1];
  float a0=0.f, a1=0.f, a2=0.f, a3=0.f;
  for (int i = s; i < e; ++i) {
    int c = col[i];
    float w = nrm[c];
    float4 v = X4[(size_t)c*48 + f4];
    a0 = fmaf(w, v.x, a0); a1 = fmaf(w, v.y, a1);
    a2 = fmaf(w, v.z, a2); a3 = fmaf(w, v.w, a3);
  }
  float nm = nrm[row];
  float4 r; r.x = a0*nm; r.y = a1*nm; r.z = a2*nm; r.w = a3*nm;
  Y4[(size_t)row*48 + f4] = r;
}
__global__ void k_nfirst(const float* __restrict__ xext, unsigned long long xOff,
                         const float* __restrict__ W, const float* __restrict__ b, int n) {
  const float* x  = xext ? xext : wsf(xOff);
  const float* x1 = wsf(OFF_X1N);
  const float* x2 = wsf(OFF_X2N);
  float* H = wsf(OFF_H32);
  int idx = blockIdx.x*blockDim.x + threadIdx.x;
  if (idx >= n*HF) return;
  int row = idx / HF, c = idx - row*HF;
  float acc = b[c];
  #pragma unroll
  for (int k = 0; k < 3; ++k) acc = fmaf(x [row*3+k], W[(0+k)*HF + c], acc);
  #pragma unroll
  for (int k = 0; k < 3; ++k) acc = fmaf(x1[row*3+k], W[(3+k)*HF + c], acc);
  #pragma unroll
  for (int k = 0; k < 3; ++k) acc = fmaf(x2[row*3+k], W[(6+k)*HF + c], acc);
  H[idx] = fmaxf(acc, 0.f);
}
// tiled fp32 mid-layer GEMM: cur = relu(H@W0+T1@W1+T2@W2+b); H = residual?0.5*(H+cur):cur
__global__ __launch_bounds__(256) void k_tgemm(
    const float* __restrict__ W, const float* __restrict__ b, int n, int residual)
{
  float* __restrict__ H = wsf(OFF_H32);
  const float* __restrict__ T1 = wsf(OFF_T132);
  const float* __restrict__ T2 = wsf(OFF_T232);
  __shared__ float Xst[BKC][68];
  __shared__ float Ws[BKC][HF];
  int t = threadIdx.x;
  int row0 = blockIdx.x * BM;
  int tx = t & 15, ty = t >> 4;
  int c0 = tx * 12;
  int r0 = ty * 4;
  float acc[4][12];
  #pragma unroll
  for (int i = 0; i < 4; ++i)
    #pragma unroll
    for (int j = 0; j < 12; ++j) acc[i][j] = 0.f;

  for (int part = 0; part < 3; ++part) {
    const float* Xp = (part == 0) ? H : (part == 1 ? T1 : T2);
    const float* Wp = W + (size_t)part * HF * HF;
    for (int kk = 0; kk < HF; kk += BKC) {
      __syncthreads();
      for (int i = t; i < 512; i += 256) {
        int r  = i >> 3;
        int c4 = (i & 7) * 4;
        int gr = row0 + r;
        float4 v = make_float4(0.f,0.f,0.f,0.f);
        if (gr < n) v = *(const float4*)&Xp[(size_t)gr*HF + kk + c4];
        Xst[c4+0][r] = v.x; Xst[c4+1][r] = v.y;
        Xst[c4+2][r] = v.z; Xst[c4+3][r] = v.w;
      }
      for (int i = t; i < 1536; i += 256) {
        int r  = i / 48;
        int c4 = (i % 48) * 4;
        *(float4*)&Ws[r][c4] = *(const float4*)&Wp[(size_t)(kk + r)*HF + c4];
      }
      __syncthreads();
      #pragma unroll
      for (int k = 0; k < BKC; ++k) {
        float4 a  = *(const float4*)&Xst[k][r0];
        float4 w0 = *(const float4*)&Ws[k][c0];
        float4 w1 = *(const float4*)&Ws[k][c0+4];
        float4 w2 = *(const float4*)&Ws[k][c0+8];
        float av[4]  = {a.x, a.y, a.z, a.w};
        float wv[12] = {w0.x,w0.y,w0.z,w0.w, w1.x,w1.y,w1.z,w1.w, w2.x,w2.y,w2.z,w2.w};
        #pragma unroll
        for (int i = 0; i < 4; ++i)
          #pragma unroll
          for (int j = 0; j < 12; ++j)
            acc[i][j] = fmaf(av[i], wv[j], acc[i][j]);
      }
    }
  }

  float bias[12];
  #pragma unroll
  for (int j = 0; j < 12; ++j) bias[j] = b[c0 + j];

  #pragma unroll
  for (int i = 0; i < 4; ++i) {
    int gr = row0 + r0 + i;
    if (gr < n) {
      size_t off = (size_t)gr*HF + c0;
      #pragma unroll
      for (int j = 0; j < 12; ++j) {
        float cur = fmaxf(acc[i][j] + bias[j], 0.f);
        float h = cur;
        if (residual) h = 0.5f*(H[off + j] + cur);
        H[off + j] = h;
      }
    }
  }
}
__global__ void k_nlast(const float* __restrict__ W, const float* __restrict__ b,
                        float* __restrict__ outb, unsigned long long outfOff,
                        int hasOutf, int n) {
  int row = blockIdx.x*blockDim.x + threadIdx.x;
  if (row >= n) return;
  const float* H  = wsf(OFF_H32);
  const float* T1 = wsf(OFF_T132);
  const float* T2 = wsf(OFF_T232);
  float a0 = b[0], a1 = b[1], a2 = b[2];
  const float* x = &H[(size_t)row*HF];
  for (int k = 0; k < HF; ++k) {
    float v = x[k]; const float* w = &W[k*3];
    a0 = fmaf(v, w[0], a0); a1 = fmaf(v, w[1], a1); a2 = fmaf(v, w[2], a2);
  }
  x = &T1[(size_t)row*HF];
  for (int k = 0; k < HF; ++k) {
    float v = x[k]; const float* w = &W[(HF+k)*3];
    a0 = fmaf(v, w[0], a0); a1 = fmaf(v, w[1], a1); a2 = fmaf(v, w[2], a2);
  }
  x = &T2[(size_t)row*HF];
  for (int k = 0; k < HF; ++k) {
    float v = x[k]; const float* w = &W[(2*HF+k)*3];
    a0 = fmaf(v, w[0], a0); a1 = fmaf(v, w[1], a1); a2 = fmaf(v, w[2], a2);
  }
  outb[row*3+0] = a0;
  outb[row*3+1] = a1;
  outb[row*3+2] = a2;
  if (hasOutf) {
    float* outf = wsf(outfOff);
    outf[row*3+0] = a0; outf[row*3+1] = a1; outf[row*3+2] = a2;
  }
}

// ======================= FUSED fp16 path (stage 3) =======================
// half2 SpMM: 2 rows per 192-thread block, 96 threads/row
__global__ __launch_bounds__(192) void k_spmm192h(int n) {
  int t = threadIdx.x;
  int sub = t / 96;
  int f2 = t - sub*96;
  int row = blockIdx.x*2 + sub;
  if (row >= n) return;
  const __half2* __restrict__ X2 = (const __half2*)wsh(OFF_HH);
  __half2* __restrict__ Y2 = (__half2*)wsh(OFF_T1H);
  const int* rowptr = wsi(OFF_RP);
  const int* col = wsi(OFF_COL);
  const float* nrm = wsf(OFF_NRM);
  int s = rowptr[row], e = rowptr[row+1];
  float ax = 0.f, ay = 0.f;
  for (int i = s; i < e; ++i) {
    int c = col[i];
    float w = nrm[c];
    float2 v = __half22float2(X2[(size_t)c*96 + f2]);
    ax = fmaf(w, v.x, ax);
    ay = fmaf(w, v.y, ay);
  }
  float nm = nrm[row];
  Y2[(size_t)row*96 + f2] = __floats2half2_rn(ax*nm, ay*nm);
}
__global__ void k_gemm_first(const float* __restrict__ xext, unsigned long long xOff,
                             const float* __restrict__ W, const float* __restrict__ b, int n) {
  const float* x  = xext ? xext : wsf(xOff);
  const float* x1 = wsf(OFF_X1F);
  const float* x2 = wsf(OFF_X2F);
  __half* H = wsh(OFF_HH);
  int idx = blockIdx.x*blockDim.x + threadIdx.x;
  if (idx >= n*HF) return;
  int row = idx / HF, c = idx - row*HF;
  float acc = b[c];
  #pragma unroll
  for (int k = 0; k < 3; ++k) acc = fmaf(x [row*3+k], W[(0+k)*HF + c], acc);
  #pragma unroll
  for (int k = 0; k < 3; ++k) acc = fmaf(x1[row*3+k], W[(3+k)*HF + c], acc);
  #pragma unroll
  for (int k = 0; k < 3; ++k) acc = fmaf(x2[row*3+k], W[(6+k)*HF + c], acc);
  H[idx] = __float2half(fmaxf(acc, 0.f));
}
__global__ __launch_bounds__(256) void k_gemm_mid(
    const float* __restrict__ W, const float* __restrict__ b, int n, int residual)
{
  __half* __restrict__ H = wsh(OFF_HH);
  const __half* __restrict__ T1 = wsh(OFF_T1H);
  const int* rowptr = wsi(OFF_RP);
  const int* col = wsi(OFF_COL);
  const float* nrm = wsf(OFF_NRM);
  __shared__ float Xst[BKC][68];
  __shared__ float Ws[BKC][HF];
  int t = threadIdx.x;
  int row0 = blockIdx.x * BM;
  int tx = t & 15, ty = t >> 4;
  int c0 = tx * 12;
  int r0 = ty * 4;
  float acc[4][12];
  #pragma unroll
  for (int i = 0; i < 4; ++i)
    #pragma unroll
    for (int j = 0; j < 12; ++j) acc[i][j] = 0.f;

  for (int part = 0; part < 3; ++part) {
    const float* Wp = W + (size_t)part * HF * HF;
    for (int kk = 0; kk < HF; kk += BKC) {
      __syncthreads();
      if (part < 2) {
        const __half* Xp = (part == 0) ? H : T1;
        for (int i = t; i < 512; i += 256) {
          int r  = i >> 3;
          int c4 = (i & 7) * 4;
          int gr = row0 + r;
          float v0=0.f, v1=0.f, v2=0.f, v3=0.f;
          if (gr < n) {
            const __half* hp = &Xp[(size_t)gr*HF + kk + c4];
            v0 = __half2float(hp[0]); v1 = __half2float(hp[1]);
            v2 = __half2float(hp[2]); v3 = __half2float(hp[3]);
          }
          Xst[c4+0][r] = v0; Xst[c4+1][r] = v1;
          Xst[c4+2][r] = v2; Xst[c4+3][r] = v3;
        }
      } else {
        for (int i = t; i < 512; i += 256) {
          int r  = i >> 3;
          int c4 = (i & 7) * 4;
          int gr = row0 + r;
          float v0=0.f, v1=0.f, v2=0.f, v3=0.f;
          if (gr < n) {
            int s = rowptr[gr], e = rowptr[gr+1];
            for (int j = s; j < e; ++j) {
              int c = col[j];
              float w = nrm[c];
              const __half* tp = &T1[(size_t)c*HF + kk + c4];
              v0 = fmaf(w, __half2float(tp[0]), v0);
              v1 = fmaf(w, __half2float(tp[1]), v1);
              v2 = fmaf(w, __half2float(tp[2]), v2);
              v3 = fmaf(w, __half2float(tp[3]), v3);
            }
            float nm = nrm[gr];
            v0 *= nm; v1 *= nm; v2 *= nm; v3 *= nm;
          }
          Xst[c4+0][r] = v0; Xst[c4+1][r] = v1;
          Xst[c4+2][r] = v2; Xst[c4+3][r] = v3;
        }
      }
      for (int i = t; i < 1536; i += 256) {
        int r  = i / 48;
        int c4 = (i % 48) * 4;
        *(float4*)&Ws[r][c4] = *(const float4*)&Wp[(size_t)(kk + r)*HF + c4];
      }
      __syncthreads();
      #pragma unroll
      for (int k = 0; k < BKC; ++k) {
        float4 a  = *(const float4*)&Xst[k][r0];
        float4 w0 = *(const float4*)&Ws[k][c0];
        float4 w1 = *(const float4*)&Ws[k][c0+4];
        float4 w2 = *(const float4*)&Ws[k][c0+8];
        float av[4]  = {a.x, a.y, a.z, a.w};
        float wv[12] = {w0.x,w0.y,w0.z,w0.w, w1.x,w1.y,w1.z,w1.w, w2.x,w2.y,w2.z,w2.w};
        #pragma unroll
        for (int i = 0; i < 4; ++i)
          #pragma unroll
          for (int j = 0; j < 12; ++j)
            acc[i][j] = fmaf(av[i], wv[j], acc[i][j]);
      }
    }
  }

  float bias[12];
  #pragma unroll
  for (int j = 0; j < 12; ++j) bias[j] = b[c0 + j];

  #pragma unroll
  for (int i = 0; i < 4; ++i) {
    int gr = row0 + r0 + i;
    if (gr < n) {
      size_t off = (size_t)gr*HF + c0;
      #pragma unroll
      for (int j = 0; j < 12; ++j) {
        float cur = fmaxf(acc[i][j] + bias[j], 0.f);
        float h = cur;
        if (residual) h = 0.5f*(__half2float(H[off + j]) + cur);
        H[off + j] = __float2half(h);
      }
    }
  }
}
__global__ void k_last(const float* __restrict__ W, const float* __restrict__ b,
                       float* __restrict__ outb, int n) {
  int row = blockIdx.x*blockDim.x + threadIdx.x;
  if (row >= n) return;
  const __half* H  = wsh(OFF_HH);
  const __half* T1 = wsh(OFF_T1H);
  const int* rowptr = wsi(OFF_RP);
  const int* col = wsi(OFF_COL);
  const float* nrm = wsf(OFF_NRM);
  float a0 = b[0], a1 = b[1], a2 = b[2];
  for (int k = 0; k < HF; ++k) {
    float v = __half2float(H[(size_t)row*HF + k]);
    const float* w = &W[k*3];
    a0 = fmaf(v, w[0], a0); a1 = fmaf(v, w[1], a1); a2 = fmaf(v, w[2], a2);
  }
  for (int k = 0; k < HF; ++k) {
    float v = __half2float(T1[(size_t)row*HF + k]);
    const float* w = &W[(HF+k)*3];
    a0 = fmaf(v, w[0], a0); a1 = fmaf(v, w[1], a1); a2 = fmaf(v, w[2], a2);
  }
  float nrow = nrm[row];
  int s = rowptr[row], e = rowptr[row+1];
  for (int i = s; i < e; ++i) {
    int c = col[i];
    float wn = nrow * nrm[c];
    float d0=0.f, d1=0.f, d2=0.f;
    const __half* tp = &T1[(size_t)c*HF];
    for (int k = 0; k < HF; ++k) {
      float v = __half2float(tp[k]);
      const float* w = &W[(2*HF+k)*3];
      d0 = fmaf(v, w[0], d0); d1 = fmaf(v, w[1], d1); d2 = fmaf(v, w[2], d2);
    }
    a0 = fmaf(wn, d0, a0); a1 = fmaf(wn, d1, a1); a2 = fmaf(wn, d2, a2);
  }
  outb[row*3+0] = a0;
  outb[row*3+1] = a1;
  outb[row*3+2] = a2;
}

// ---------------- unpool: ws f32 in -> ws f32 shadow + f32 out ----------------
__global__ void k_unpool(unsigned long long srcOff, const int* __restrict__ pidx,
                         unsigned long long dstfOff, float* __restrict__ dstb,
                         int n, int P) {
  const float* src = wsf(srcOff);
  float* dstf = wsf(dstfOff);
  int i = blockIdx.x*blockDim.x + threadIdx.x;
  if (i >= n + P) return;
  float v0, v1, v2;
  if (i < n) {
    v0 = src[i*3+0]; v1 = src[i*3+1]; v2 = src[i*3+2];
  } else {
    int a = pidx[(i-n)*2], c = pidx[(i-n)*2+1];
    v0 = 0.5f*(src[a*3+0] + src[c*3+0]);
    v1 = 0.5f*(src[a*3+1] + src[c*3+1]);
    v2 = 0.5f*(src[a*3+2] + src[c*3+2]);
  }
  dstf[i*3+0] = v0; dstf[i*3+1] = v1; dstf[i*3+2] = v2;
  dstb[i*3+0] = v0;
  dstb[i*3+1] = v1;
  dstb[i*3+2] = v2;
}

extern "C" void kernel_launch(void* const* d_in, const int* in_sizes, int n_in,
                              void* d_out, int out_size, void* d_ws, size_t ws_size,
                              hipStream_t stream) {
  (void)in_sizes; (void)n_in; (void)out_size; (void)d_ws; (void)ws_size;
  const float* features = (const float*)d_in[0];
  const int*  src0  = (const int*)d_in[1];
  const int*  dst0  = (const int*)d_in[2];
  const int*  pool0 = (const int*)d_in[3];
  const int*  edge0 = (const int*)d_in[4];
  const int*  pool1 = (const int*)d_in[5];
  const int*  edge1 = (const int*)d_in[6];
  const float* Wf = (const float*)d_in[7];
  const float* bfp = (const float*)d_in[8];
  const float* Wm = (const float*)d_in[9];
  const float* bm = (const float*)d_in[10];
  const float* Wl = (const float*)d_in[11];
  const float* bl = (const float*)d_in[12];
  float* out = (float*)d_out;   // reference outputs are float32

  auto csr = [&](int n, const int* srcD, const int* dstD, int Edir,
                 const int* edgeB, int Eund) {
    k_zero<<<divup(n,256),256,0,stream>>>(OFF_DEG, n);
    if (srcD) k_count_direct<<<divup(Edir,256),256,0,stream>>>(dstD, Edir);
    else      k_count_bidir <<<divup(Eund,256),256,0,stream>>>(edgeB, Eund);
    k_norm<<<divup(n,256),256,0,stream>>>(n);
    k_exscan<<<1,1024,0,stream>>>(n);
    k_copyi<<<divup(n,256),256,0,stream>>>(OFF_RP, OFF_DEG, n);
    if (srcD) k_fill_direct<<<divup(Edir,256),256,0,stream>>>(srcD, dstD, Edir);
    else      k_fill_bidir <<<divup(Eund,256),256,0,stream>>>(edgeB, Eund);
  };

  auto stage_naive = [&](const float* xext, unsigned long long xOff, int n,
                         const int* srcD, const int* dstD, int Edir,
                         const int* edgeB, int Eund,
                         int s, float* outb, unsigned long long outfOff, int hasOutf) {
    csr(n, srcD, dstD, Edir, edgeB, Eund);
    k_spmm3<<<divup(n,256),256,0,stream>>>(xext, xOff, OFF_X1N, n);
    k_spmm3<<<divup(n,256),256,0,stream>>>(nullptr, OFF_X1N, OFF_X2N, n);
    k_nfirst<<<divup(n*HF,256),256,0,stream>>>(xext, xOff, Wf + (size_t)s*9*HF, bfp + s*HF, n);
    int gsp = divup(n*48,192);
    for (int it = 0; it < 12; ++it) {
      k_nspmm4<<<gsp,192,0,stream>>>(OFF_H32,  OFF_T132, n);
      k_nspmm4<<<gsp,192,0,stream>>>(OFF_T132, OFF_T232, n);
      k_tgemm<<<divup(n,BM),256,0,stream>>>(Wm + ((size_t)s*12 + it)*576*HF,
          bm + (s*12+it)*HF, n, ((it+1)%2==0) ? 1 : 0);
    }
    k_nspmm4<<<gsp,192,0,stream>>>(OFF_H32,  OFF_T132, n);
    k_nspmm4<<<gsp,192,0,stream>>>(OFF_T132, OFF_T232, n);
    k_nlast<<<divup(n,256),256,0,stream>>>(Wl + (size_t)s*576*3, bl + s*3, outb, outfOff, hasOutf, n);
  };

  auto stage_fused = [&](unsigned long long xOff, int n,
                         const int* edgeB, int Eund,
                         int s, float* outb) {
    csr(n, nullptr, nullptr, 0, edgeB, Eund);
    k_spmm3<<<divup(n,256),256,0,stream>>>(nullptr, xOff, OFF_X1F, n);
    k_spmm3<<<divup(n,256),256,0,stream>>>(nullptr, OFF_X1F, OFF_X2F, n);
    k_gemm_first<<<divup(n*HF,256),256,0,stream>>>(nullptr, xOff, Wf + (size_t)s*9*HF, bfp + s*HF, n);
    int gsp = divup(n,2);
    for (int it = 0; it < 12; ++it) {
      k_spmm192h<<<gsp,192,0,stream>>>(n);
      k_gemm_mid<<<divup(n,BM),256,0,stream>>>(
          Wm + ((size_t)s*12 + it)*576*HF, bm + (s*12+it)*HF, n, ((it+1)%2==0) ? 1 : 0);
    }
    k_spmm192h<<<gsp,192,0,stream>>>(n);
    k_last<<<divup(n,256),256,0,stream>>>(Wl + (size_t)s*576*3, bl + s*3, outb, n);
  };

  // stage 1: n=10000, direct edges (fp32)
  stage_naive(features, 0ull, 10000, src0, dst0, 60000, nullptr, 0, 0,
              out + 0, OFF_O1F, 1);
  k_unpool<<<divup(40000,256),256,0,stream>>>(OFF_O1F, pool0, OFF_U1F, out + 630000, 10000, 30000);
  // stage 2: n=40000, bidir edge0 (fp32)
  stage_naive(nullptr, OFF_U1F, 40000, nullptr, nullptr, 0, edge0, 120000, 1,
              out + 30000, OFF_O2F, 1);
  k_unpool<<<divup(160000,256),256,0,stream>>>(OFF_O2F, pool1, OFF_U2F, out + 750000, 40000, 120000);
  // stage 3: n=160000, bidir edge1 (fused fp16)
  stage_fused(OFF_U2F, 160000, edge1, 480000, 2, out + 150000);
}

// Round 18
// 13225.005 us; speedup vs baseline: 2.3225x; 1.1989x over previous
//
#include <hip/hip_runtime.h>
#include <hip/hip_fp16.h>

#define HF 192
#define BM 64
#define BKC 32

static inline int divup(int a, int b){ return (a+b-1)/b; }

typedef _Float16 half8 __attribute__((ext_vector_type(8)));
typedef float f32x4 __attribute__((ext_vector_type(4)));

// ---- static device workspace, 195,734,272 B ----
#define G_WS_BYTES 195734272ull
__device__ __align__(256) char g_ws[G_WS_BYTES];

// stages 1/2 (fp32, n <= 40000) alias [0 .. 122,880,000):
#define OFF_H32   0ull
#define OFF_T132  30720000ull
#define OFF_T232  61440000ull
#define OFF_CUR32 92160000ull
// stage 3 (fp16, n = 160000) uses [0 .. 184,320,000):
#define OFF_HH    0ull
#define OFF_T1H   61440000ull
#define OFF_T2H   122880000ull
// CSR / small buffers (above both)
#define OFF_DEG  184320000ull
#define OFF_RP   184960000ull
#define OFF_COL  185600032ull
#define OFF_NRM  189440032ull
#define OFF_O1F  190080032ull
#define OFF_U1F  190200032ull
#define OFF_O2F  190680032ull
#define OFF_U2F  191160032ull
#define OFF_WT   193080032ull   // 12 layers x [192 cols][576 k] fp16 = 2,654,208 B
#define OFF_X1N  OFF_T132
#define OFF_X2N  (OFF_T132 + 1920000ull)
#define OFF_X1F  OFF_T1H
#define OFF_X2F  (OFF_T1H + 1920000ull)

__device__ __forceinline__ float*  wsf(unsigned long long o){ return (float*) (g_ws + o); }
__device__ __forceinline__ int*    wsi(unsigned long long o){ return (int*)   (g_ws + o); }
__device__ __forceinline__ __half* wsh(unsigned long long o){ return (__half*)(g_ws + o); }

// ---------------- utility ----------------
__global__ void k_zero(unsigned long long off, int n) {
  int i = blockIdx.x*blockDim.x + threadIdx.x;
  if (i < n) wsi(off)[i] = 0;
}
__global__ void k_copyi(unsigned long long aOff, unsigned long long bOff, int n) {
  int i = blockIdx.x*blockDim.x + threadIdx.x;
  if (i < n) wsi(bOff)[i] = wsi(aOff)[i];
}

// ---------------- CSR build ----------------
__global__ void k_count_direct(const int* __restrict__ dst, int E) {
  int* deg = wsi(OFF_DEG);
  int e = blockIdx.x*blockDim.x + threadIdx.x;
  if (e < E) atomicAdd(&deg[dst[e]], 1);
}
__global__ void k_count_bidir(const int* __restrict__ edge, int E) {
  int* deg = wsi(OFF_DEG);
  int e = blockIdx.x*blockDim.x + threadIdx.x;
  if (e < E) {
    atomicAdd(&deg[edge[2*e+1]], 1);
    atomicAdd(&deg[edge[2*e  ]], 1);
  }
}
__global__ void k_norm(int n) {
  const int* deg = wsi(OFF_DEG);
  float* nrm = wsf(OFF_NRM);
  int i = blockIdx.x*blockDim.x + threadIdx.x;
  if (i < n) {
    int d = deg[i]; if (d < 1) d = 1;
    nrm[i] = rsqrtf((float)d);
  }
}
__global__ __launch_bounds__(1024) void k_exscan(int n) {
  const int* in = wsi(OFF_DEG);
  int* out = wsi(OFF_RP);
  __shared__ int sm[1024];
  int t = threadIdx.x;
  int carry = 0;
  for (int base = 0; base < n; base += 4096) {
    int idx = base + t*4;
    int v0 = (idx+0 < n) ? in[idx+0] : 0;
    int v1 = (idx+1 < n) ? in[idx+1] : 0;
    int v2 = (idx+2 < n) ? in[idx+2] : 0;
    int v3 = (idx+3 < n) ? in[idx+3] : 0;
    int s = v0+v1+v2+v3;
    sm[t] = s;
    __syncthreads();
    for (int off = 1; off < 1024; off <<= 1) {
      int u = (t >= off) ? sm[t-off] : 0;
      __syncthreads();
      sm[t] += u;
      __syncthreads();
    }
    int excl = carry + sm[t] - s;
    if (idx   < n) out[idx]   = excl;
    if (idx+1 < n) out[idx+1] = excl + v0;
    if (idx+2 < n) out[idx+2] = excl + v0+v1;
    if (idx+3 < n) out[idx+3] = excl + v0+v1+v2;
    carry += sm[1023];
    __syncthreads();
  }
  if (t == 0) out[n] = carry;
}
__global__ void k_fill_direct(const int* __restrict__ src, const int* __restrict__ dst, int E) {
  int* cur = wsi(OFF_DEG);
  int* col = wsi(OFF_COL);
  int e = blockIdx.x*blockDim.x + threadIdx.x;
  if (e < E) {
    int p = atomicAdd(&cur[dst[e]], 1);
    col[p] = src[e];
  }
}
__global__ void k_fill_bidir(const int* __restrict__ edge, int E) {
  int* cur = wsi(OFF_DEG);
  int* col = wsi(OFF_COL);
  int e = blockIdx.x*blockDim.x + threadIdx.x;
  if (e < E) {
    int u = edge[2*e], v = edge[2*e+1];
    int p = atomicAdd(&cur[v], 1); col[p] = u;
    int q = atomicAdd(&cur[u], 1); col[q] = v;
  }
}

// ---------------- propagation dim-3 (f32) ----------------
__global__ void k_spmm3(const float* __restrict__ Xext, unsigned long long Xoff,
                        unsigned long long Yoff, int n) {
  const float* X = Xext ? Xext : wsf(Xoff);
  float* Y = wsf(Yoff);
  const int* rowptr = wsi(OFF_RP);
  const int* col = wsi(OFF_COL);
  const float* nrm = wsf(OFF_NRM);
  int row = blockIdx.x*blockDim.x + threadIdx.x;
  if (row >= n) return;
  int s = rowptr[row], e = rowptr[row+1];
  float a0=0.f, a1=0.f, a2=0.f;
  for (int i = s; i < e; ++i) {
    int c = col[i]; float v = nrm[c];
    a0 = fmaf(v, X[c*3+0], a0);
    a1 = fmaf(v, X[c*3+1], a1);
    a2 = fmaf(v, X[c*3+2], a2);
  }
  float nm = nrm[row];
  Y[row*3+0] = a0*nm; Y[row*3+1] = a1*nm; Y[row*3+2] = a2*nm;
}

// ======================= fp32 path (stages 1 & 2) =======================
__global__ __launch_bounds__(192) void k_nspmm4(unsigned long long Xoff,
                                                unsigned long long Yoff, int n) {
  int gid = blockIdx.x*192 + threadIdx.x;
  if (gid >= n*48) return;
  int row = gid / 48, f4 = gid - row*48;
  const float4* __restrict__ X4 = (const float4*)wsf(Xoff);
  float4* __restrict__ Y4 = (float4*)wsf(Yoff);
  const int* rowptr = wsi(OFF_RP);
  const int* col = wsi(OFF_COL);
  const float* nrm = wsf(OFF_NRM);
  int s = rowptr[row], e = rowptr[row+1];
  float a0=0.f, a1=0.f, a2=0.f, a3=0.f;
  for (int i = s; i < e; ++i) {
    int c = col[i];
    float w = nrm[c];
    float4 v = X4[(size_t)c*48 + f4];
    a0 = fmaf(w, v.x, a0); a1 = fmaf(w, v.y, a1);
    a2 = fmaf(w, v.z, a2); a3 = fmaf(w, v.w, a3);
  }
  float nm = nrm[row];
  float4 r; r.x = a0*nm; r.y = a1*nm; r.z = a2*nm; r.w = a3*nm;
  Y4[(size_t)row*48 + f4] = r;
}
__global__ void k_nfirst(const float* __restrict__ xext, unsigned long long xOff,
                         const float* __restrict__ W, const float* __restrict__ b, int n) {
  const float* x  = xext ? xext : wsf(xOff);
  const float* x1 = wsf(OFF_X1N);
  const float* x2 = wsf(OFF_X2N);
  float* H = wsf(OFF_H32);
  int idx = blockIdx.x*blockDim.x + threadIdx.x;
  if (idx >= n*HF) return;
  int row = idx / HF, c = idx - row*HF;
  float acc = b[c];
  #pragma unroll
  for (int k = 0; k < 3; ++k) acc = fmaf(x [row*3+k], W[(0+k)*HF + c], acc);
  #pragma unroll
  for (int k = 0; k < 3; ++k) acc = fmaf(x1[row*3+k], W[(3+k)*HF + c], acc);
  #pragma unroll
  for (int k = 0; k < 3; ++k) acc = fmaf(x2[row*3+k], W[(6+k)*HF + c], acc);
  H[idx] = fmaxf(acc, 0.f);
}
__global__ __launch_bounds__(256) void k_tgemm(
    const float* __restrict__ W, const float* __restrict__ b, int n, int residual)
{
  float* __restrict__ H = wsf(OFF_H32);
  const float* __restrict__ T1 = wsf(OFF_T132);
  const float* __restrict__ T2 = wsf(OFF_T232);
  __shared__ float Xst[BKC][68];
  __shared__ float Ws[BKC][HF];
  int t = threadIdx.x;
  int row0 = blockIdx.x * BM;
  int tx = t & 15, ty = t >> 4;
  int c0 = tx * 12;
  int r0 = ty * 4;
  float acc[4][12];
  #pragma unroll
  for (int i = 0; i < 4; ++i)
    #pragma unroll
    for (int j = 0; j < 12; ++j) acc[i][j] = 0.f;

  for (int part = 0; part < 3; ++part) {
    const float* Xp = (part == 0) ? H : (part == 1 ? T1 : T2);
    const float* Wp = W + (size_t)part * HF * HF;
    for (int kk = 0; kk < HF; kk += BKC) {
      __syncthreads();
      for (int i = t; i < 512; i += 256) {
        int r  = i >> 3;
        int c4 = (i & 7) * 4;
        int gr = row0 + r;
        float4 v = make_float4(0.f,0.f,0.f,0.f);
        if (gr < n) v = *(const float4*)&Xp[(size_t)gr*HF + kk + c4];
        Xst[c4+0][r] = v.x; Xst[c4+1][r] = v.y;
        Xst[c4+2][r] = v.z; Xst[c4+3][r] = v.w;
      }
      for (int i = t; i < 1536; i += 256) {
        int r  = i / 48;
        int c4 = (i % 48) * 4;
        *(float4*)&Ws[r][c4] = *(const float4*)&Wp[(size_t)(kk + r)*HF + c4];
      }
      __syncthreads();
      #pragma unroll
      for (int k = 0; k < BKC; ++k) {
        float4 a  = *(const float4*)&Xst[k][r0];
        float4 w0 = *(const float4*)&Ws[k][c0];
        float4 w1 = *(const float4*)&Ws[k][c0+4];
        float4 w2 = *(const float4*)&Ws[k][c0+8];
        float av[4]  = {a.x, a.y, a.z, a.w};
        float wv[12] = {w0.x,w0.y,w0.z,w0.w, w1.x,w1.y,w1.z,w1.w, w2.x,w2.y,w2.z,w2.w};
        #pragma unroll
        for (int i = 0; i < 4; ++i)
          #pragma unroll
          for (int j = 0; j < 12; ++j)
            acc[i][j] = fmaf(av[i], wv[j], acc[i][j]);
      }
    }
  }

  float bias[12];
  #pragma unroll
  for (int j = 0; j < 12; ++j) bias[j] = b[c0 + j];

  #pragma unroll
  for (int i = 0; i < 4; ++i) {
    int gr = row0 + r0 + i;
    if (gr < n) {
      size_t off = (size_t)gr*HF + c0;
      #pragma unroll
      for (int j = 0; j < 12; ++j) {
        float cur = fmaxf(acc[i][j] + bias[j], 0.f);
        float h = cur;
        if (residual) h = 0.5f*(H[off + j] + cur);
        H[off + j] = h;
      }
    }
  }
}
__global__ void k_nlast(const float* __restrict__ W, const float* __restrict__ b,
                        float* __restrict__ outb, unsigned long long outfOff,
                        int hasOutf, int n) {
  int row = blockIdx.x*blockDim.x + threadIdx.x;
  if (row >= n) return;
  const float* H  = wsf(OFF_H32);
  const float* T1 = wsf(OFF_T132);
  const float* T2 = wsf(OFF_T232);
  float a0 = b[0], a1 = b[1], a2 = b[2];
  const float* x = &H[(size_t)row*HF];
  for (int k = 0; k < HF; ++k) {
    float v = x[k]; const float* w = &W[k*3];
    a0 = fmaf(v, w[0], a0); a1 = fmaf(v, w[1], a1); a2 = fmaf(v, w[2], a2);
  }
  x = &T1[(size_t)row*HF];
  for (int k = 0; k < HF; ++k) {
    float v = x[k]; const float* w = &W[(HF+k)*3];
    a0 = fmaf(v, w[0], a0); a1 = fmaf(v, w[1], a1); a2 = fmaf(v, w[2], a2);
  }
  x = &T2[(size_t)row*HF];
  for (int k = 0; k < HF; ++k) {
    float v = x[k]; const float* w = &W[(2*HF+k)*3];
    a0 = fmaf(v, w[0], a0); a1 = fmaf(v, w[1], a1); a2 = fmaf(v, w[2], a2);
  }
  outb[row*3+0] = a0;
  outb[row*3+1] = a1;
  outb[row*3+2] = a2;
  if (hasOutf) {
    float* outf = wsf(outfOff);
    outf[row*3+0] = a0; outf[row*3+1] = a1; outf[row*3+2] = a2;
  }
}

// ======================= fp16 path (stage 3) =======================
// half2 SpMM with explicit src/dst: 2 rows per 192-thread block
__global__ __launch_bounds__(192) void k_spmm192h(unsigned long long Xoff,
                                                  unsigned long long Yoff, int n) {
  int t = threadIdx.x;
  int sub = t / 96;
  int f2 = t - sub*96;
  int row = blockIdx.x*2 + sub;
  if (row >= n) return;
  const __half2* __restrict__ X2 = (const __half2*)wsh(Xoff);
  __half2* __restrict__ Y2 = (__half2*)wsh(Yoff);
  const int* rowptr = wsi(OFF_RP);
  const int* col = wsi(OFF_COL);
  const float* nrm = wsf(OFF_NRM);
  int s = rowptr[row], e = rowptr[row+1];
  float ax = 0.f, ay = 0.f;
  for (int i = s; i < e; ++i) {
    int c = col[i];
    float w = nrm[c];
    float2 v = __half22float2(X2[(size_t)c*96 + f2]);
    ax = fmaf(w, v.x, ax);
    ay = fmaf(w, v.y, ay);
  }
  float nm = nrm[row];
  Y2[(size_t)row*96 + f2] = __floats2half2_rn(ax*nm, ay*nm);
}
__global__ void k_gemm_first(const float* __restrict__ xext, unsigned long long xOff,
                             const float* __restrict__ W, const float* __restrict__ b, int n) {
  const float* x  = xext ? xext : wsf(xOff);
  const float* x1 = wsf(OFF_X1F);
  const float* x2 = wsf(OFF_X2F);
  __half* H = wsh(OFF_HH);
  int idx = blockIdx.x*blockDim.x + threadIdx.x;
  if (idx >= n*HF) return;
  int row = idx / HF, c = idx - row*HF;
  float acc = b[c];
  #pragma unroll
  for (int k = 0; k < 3; ++k) acc = fmaf(x [row*3+k], W[(0+k)*HF + c], acc);
  #pragma unroll
  for (int k = 0; k < 3; ++k) acc = fmaf(x1[row*3+k], W[(3+k)*HF + c], acc);
  #pragma unroll
  for (int k = 0; k < 3; ++k) acc = fmaf(x2[row*3+k], W[(6+k)*HF + c], acc);
  H[idx] = __float2half(fmaxf(acc, 0.f));
}
// W prep: Wt[it][col][k] = fp16(Wm[stage it][k][col]), 12 layers of current stage
__global__ void k_wprep(const float* __restrict__ Wm, int s) {
  int idx = blockIdx.x*blockDim.x + threadIdx.x;
  if (idx >= 12*576*HF) return;
  int it = idx / (576*HF);
  int rem = idx - it*576*HF;
  int k = rem / HF;
  int c = rem - k*HF;
  wsh(OFF_WT)[(size_t)it*HF*576 + (size_t)c*576 + k] =
      __float2half(Wm[((size_t)(s*12+it)*576 + k)*HF + c]);
}
// MFMA mid layer: H = f(H@W0 + T1@W1 + T2@W2 + b), 64 rows x 192 cols per block
__global__ __launch_bounds__(256) void k_mfma_mid(
    const float* __restrict__ b, int it, int n, int residual)
{
  __half* __restrict__ H = wsh(OFF_HH);
  const __half* __restrict__ T1 = wsh(OFF_T1H);
  const __half* __restrict__ T2 = wsh(OFF_T2H);
  const __half* __restrict__ Wt = wsh(OFF_WT) + (size_t)it*HF*576;
  int t = threadIdx.x;
  int w = t >> 6;
  int l = t & 63;
  int lr = l & 15;   // row (A) / col (B,C)
  int lg = l >> 4;   // k-group
  int row0 = blockIdx.x*64 + w*16;

  f32x4 acc[12];
  #pragma unroll
  for (int i = 0; i < 12; ++i) acc[i] = (f32x4){0.f,0.f,0.f,0.f};

  const __half* Xp[3] = { H, T1, T2 };
  for (int p = 0; p < 3; ++p) {
    const __half* X = Xp[p];
    #pragma unroll
    for (int k0 = 0; k0 < HF; k0 += 32) {
      half8 a = *(const half8*)&X[(size_t)(row0 + lr)*HF + k0 + lg*8];
      #pragma unroll
      for (int tl = 0; tl < 12; ++tl) {
        half8 bb = *(const half8*)&Wt[(size_t)(tl*16 + lr)*576 + p*HF + k0 + lg*8];
        acc[tl] = __builtin_amdgcn_mfma_f32_16x16x32_f16(a, bb, acc[tl], 0, 0, 0);
      }
    }
  }

  #pragma unroll
  for (int tl = 0; tl < 12; ++tl) {
    int c = tl*16 + lr;
    float bias = b[c];
    #pragma unroll
    for (int j = 0; j < 4; ++j) {
      int row = row0 + lg*4 + j;
      size_t o = (size_t)row*HF + c;
      float cur = fmaxf(acc[tl][j] + bias, 0.f);
      float h = cur;
      if (residual) h = 0.5f*(__half2float(H[o]) + cur);
      H[o] = __float2half(h);
    }
  }
}
// last layer, linear T2 reads
__global__ void k_last_lin(const float* __restrict__ W, const float* __restrict__ b,
                           float* __restrict__ outb, int n) {
  int row = blockIdx.x*blockDim.x + threadIdx.x;
  if (row >= n) return;
  const __half* H  = wsh(OFF_HH);
  const __half* T1 = wsh(OFF_T1H);
  const __half* T2 = wsh(OFF_T2H);
  float a0 = b[0], a1 = b[1], a2 = b[2];
  const __half* x = &H[(size_t)row*HF];
  for (int k = 0; k < HF; ++k) {
    float v = __half2float(x[k]); const float* w = &W[k*3];
    a0 = fmaf(v, w[0], a0); a1 = fmaf(v, w[1], a1); a2 = fmaf(v, w[2], a2);
  }
  x = &T1[(size_t)row*HF];
  for (int k = 0; k < HF; ++k) {
    float v = __half2float(x[k]); const float* w = &W[(HF+k)*3];
    a0 = fmaf(v, w[0], a0); a1 = fmaf(v, w[1], a1); a2 = fmaf(v, w[2], a2);
  }
  x = &T2[(size_t)row*HF];
  for (int k = 0; k < HF; ++k) {
    float v = __half2float(x[k]); const float* w = &W[(2*HF+k)*3];
    a0 = fmaf(v, w[0], a0); a1 = fmaf(v, w[1], a1); a2 = fmaf(v, w[2], a2);
  }
  outb[row*3+0] = a0;
  outb[row*3+1] = a1;
  outb[row*3+2] = a2;
}

// ---------------- unpool ----------------
__global__ void k_unpool(unsigned long long srcOff, const int* __restrict__ pidx,
                         unsigned long long dstfOff, float* __restrict__ dstb,
                         int n, int P) {
  const float* src = wsf(srcOff);
  float* dstf = wsf(dstfOff);
  int i = blockIdx.x*blockDim.x + threadIdx.x;
  if (i >= n + P) return;
  float v0, v1, v2;
  if (i < n) {
    v0 = src[i*3+0]; v1 = src[i*3+1]; v2 = src[i*3+2];
  } else {
    int a = pidx[(i-n)*2], c = pidx[(i-n)*2+1];
    v0 = 0.5f*(src[a*3+0] + src[c*3+0]);
    v1 = 0.5f*(src[a*3+1] + src[c*3+1]);
    v2 = 0.5f*(src[a*3+2] + src[c*3+2]);
  }
  dstf[i*3+0] = v0; dstf[i*3+1] = v1; dstf[i*3+2] = v2;
  dstb[i*3+0] = v0;
  dstb[i*3+1] = v1;
  dstb[i*3+2] = v2;
}

extern "C" void kernel_launch(void* const* d_in, const int* in_sizes, int n_in,
                              void* d_out, int out_size, void* d_ws, size_t ws_size,
                              hipStream_t stream) {
  (void)in_sizes; (void)n_in; (void)out_size; (void)d_ws; (void)ws_size;
  const float* features = (const float*)d_in[0];
  const int*  src0  = (const int*)d_in[1];
  const int*  dst0  = (const int*)d_in[2];
  const int*  pool0 = (const int*)d_in[3];
  const int*  edge0 = (const int*)d_in[4];
  const int*  pool1 = (const int*)d_in[5];
  const int*  edge1 = (const int*)d_in[6];
  const float* Wf = (const float*)d_in[7];
  const float* bfp = (const float*)d_in[8];
  const float* Wm = (const float*)d_in[9];
  const float* bm = (const float*)d_in[10];
  const float* Wl = (const float*)d_in[11];
  const float* bl = (const float*)d_in[12];
  float* out = (float*)d_out;

  auto csr = [&](int n, const int* srcD, const int* dstD, int Edir,
                 const int* edgeB, int Eund) {
    k_zero<<<divup(n,256),256,0,stream>>>(OFF_DEG, n);
    if (srcD) k_count_direct<<<divup(Edir,256),256,0,stream>>>(dstD, Edir);
    else      k_count_bidir <<<divup(Eund,256),256,0,stream>>>(edgeB, Eund);
    k_norm<<<divup(n,256),256,0,stream>>>(n);
    k_exscan<<<1,1024,0,stream>>>(n);
    k_copyi<<<divup(n,256),256,0,stream>>>(OFF_RP, OFF_DEG, n);
    if (srcD) k_fill_direct<<<divup(Edir,256),256,0,stream>>>(srcD, dstD, Edir);
    else      k_fill_bidir <<<divup(Eund,256),256,0,stream>>>(edgeB, Eund);
  };

  auto stage_naive = [&](const float* xext, unsigned long long xOff, int n,
                         const int* srcD, const int* dstD, int Edir,
                         const int* edgeB, int Eund,
                         int s, float* outb, unsigned long long outfOff, int hasOutf) {
    csr(n, srcD, dstD, Edir, edgeB, Eund);
    k_spmm3<<<divup(n,256),256,0,stream>>>(xext, xOff, OFF_X1N, n);
    k_spmm3<<<divup(n,256),256,0,stream>>>(nullptr, OFF_X1N, OFF_X2N, n);
    k_nfirst<<<divup(n*HF,256),256,0,stream>>>(xext, xOff, Wf + (size_t)s*9*HF, bfp + s*HF, n);
    int gsp = divup(n*48,192);
    for (int it = 0; it < 12; ++it) {
      k_nspmm4<<<gsp,192,0,stream>>>(OFF_H32,  OFF_T132, n);
      k_nspmm4<<<gsp,192,0,stream>>>(OFF_T132, OFF_T232, n);
      k_tgemm<<<divup(n,BM),256,0,stream>>>(Wm + ((size_t)s*12 + it)*576*HF,
          bm + (s*12+it)*HF, n, ((it+1)%2==0) ? 1 : 0);
    }
    k_nspmm4<<<gsp,192,0,stream>>>(OFF_H32,  OFF_T132, n);
    k_nspmm4<<<gsp,192,0,stream>>>(OFF_T132, OFF_T232, n);
    k_nlast<<<divup(n,256),256,0,stream>>>(Wl + (size_t)s*576*3, bl + s*3, outb, outfOff, hasOutf, n);
  };

  auto stage_fused = [&](unsigned long long xOff, int n,
                         const int* edgeB, int Eund,
                         int s, float* outb) {
    csr(n, nullptr, nullptr, 0, edgeB, Eund);
    k_wprep<<<divup(12*576*HF,256),256,0,stream>>>(Wm, s);
    k_spmm3<<<divup(n,256),256,0,stream>>>(nullptr, xOff, OFF_X1F, n);
    k_spmm3<<<divup(n,256),256,0,stream>>>(nullptr, OFF_X1F, OFF_X2F, n);
    k_gemm_first<<<divup(n*HF,256),256,0,stream>>>(nullptr, xOff, Wf + (size_t)s*9*HF, bfp + s*HF, n);
    int gsp = divup(n,2);
    for (int it = 0; it < 12; ++it) {
      k_spmm192h<<<gsp,192,0,stream>>>(OFF_HH,  OFF_T1H, n);
      k_spmm192h<<<gsp,192,0,stream>>>(OFF_T1H, OFF_T2H, n);
      k_mfma_mid<<<divup(n,64),256,0,stream>>>(bm + (s*12+it)*HF, it, n, ((it+1)%2==0) ? 1 : 0);
    }
    k_spmm192h<<<gsp,192,0,stream>>>(OFF_HH,  OFF_T1H, n);
    k_spmm192h<<<gsp,192,0,stream>>>(OFF_T1H, OFF_T2H, n);
    k_last_lin<<<divup(n,256),256,0,stream>>>(Wl + (size_t)s*576*3, bl + s*3, outb, n);
  };

  // stage 1: n=10000, direct edges (fp32)
  stage_naive(features, 0ull, 10000, src0, dst0, 60000, nullptr, 0, 0,
              out + 0, OFF_O1F, 1);
  k_unpool<<<divup(40000,256),256,0,stream>>>(OFF_O1F, pool0, OFF_U1F, out + 630000, 10000, 30000);
  // stage 2: n=40000, bidir edge0 (fp32)
  stage_naive(nullptr, OFF_U1F, 40000, nullptr, nullptr, 0, edge0, 120000, 1,
              out + 30000, OFF_O2F, 1);
  k_unpool<<<divup(160000,256),256,0,stream>>>(OFF_O2F, pool1, OFF_U2F, out + 750000, 40000, 120000);
  // stage 3: n=160000, bidir edge1 (fp16 + MFMA)
  stage_fused(OFF_U2F, 160000, edge1, 480000, 2, out + 150000);
}

// Round 19
// 5936.936 us; speedup vs baseline: 5.1735x; 2.2276x over previous
//
#include <hip/hip_runtime.h>
#include <hip/hip_fp16.h>

#define HF 192

static inline int divup(int a, int b){ return (a+b-1)/b; }

typedef _Float16 half8 __attribute__((ext_vector_type(8)));
typedef float f32x4 __attribute__((ext_vector_type(4)));

// ---- static device workspace, 195,734,272 B ----
#define G_WS_BYTES 195734272ull
__device__ __align__(256) char g_ws[G_WS_BYTES];

// fp16 node buffers (up to n=160000)
#define OFF_HH    0ull
#define OFF_T1H   61440000ull
#define OFF_T2H   122880000ull
// CSR / small buffers
#define OFF_DEG  184320000ull
#define OFF_RP   184960000ull
#define OFF_COL  185600032ull
#define OFF_NRM  189440032ull
#define OFF_O1F  190080032ull
#define OFF_U1F  190200032ull
#define OFF_O2F  190680032ull
#define OFF_U2F  191160032ull
#define OFF_WT   193080032ull   // 12 layers x [192 cols][576 k] fp16
// fp32 dim-3 temps alias the (not-yet-live) T1H region
#define OFF_X1F  OFF_T1H
#define OFF_X2F  (OFF_T1H + 1920000ull)

__device__ __forceinline__ float*  wsf(unsigned long long o){ return (float*) (g_ws + o); }
__device__ __forceinline__ int*    wsi(unsigned long long o){ return (int*)   (g_ws + o); }
__device__ __forceinline__ __half* wsh(unsigned long long o){ return (__half*)(g_ws + o); }

// ---------------- utility ----------------
__global__ void k_zero(unsigned long long off, int n) {
  int i = blockIdx.x*blockDim.x + threadIdx.x;
  if (i < n) wsi(off)[i] = 0;
}
__global__ void k_copyi(unsigned long long aOff, unsigned long long bOff, int n) {
  int i = blockIdx.x*blockDim.x + threadIdx.x;
  if (i < n) wsi(bOff)[i] = wsi(aOff)[i];
}

// ---------------- CSR build ----------------
__global__ void k_count_direct(const int* __restrict__ dst, int E) {
  int* deg = wsi(OFF_DEG);
  int e = blockIdx.x*blockDim.x + threadIdx.x;
  if (e < E) atomicAdd(&deg[dst[e]], 1);
}
__global__ void k_count_bidir(const int* __restrict__ edge, int E) {
  int* deg = wsi(OFF_DEG);
  int e = blockIdx.x*blockDim.x + threadIdx.x;
  if (e < E) {
    atomicAdd(&deg[edge[2*e+1]], 1);
    atomicAdd(&deg[edge[2*e  ]], 1);
  }
}
__global__ void k_norm(int n) {
  const int* deg = wsi(OFF_DEG);
  float* nrm = wsf(OFF_NRM);
  int i = blockIdx.x*blockDim.x + threadIdx.x;
  if (i < n) {
    int d = deg[i]; if (d < 1) d = 1;
    nrm[i] = rsqrtf((float)d);
  }
}
__global__ __launch_bounds__(1024) void k_exscan(int n) {
  const int* in = wsi(OFF_DEG);
  int* out = wsi(OFF_RP);
  __shared__ int sm[1024];
  int t = threadIdx.x;
  int carry = 0;
  for (int base = 0; base < n; base += 4096) {
    int idx = base + t*4;
    int v0 = (idx+0 < n) ? in[idx+0] : 0;
    int v1 = (idx+1 < n) ? in[idx+1] : 0;
    int v2 = (idx+2 < n) ? in[idx+2] : 0;
    int v3 = (idx+3 < n) ? in[idx+3] : 0;
    int s = v0+v1+v2+v3;
    sm[t] = s;
    __syncthreads();
    for (int off = 1; off < 1024; off <<= 1) {
      int u = (t >= off) ? sm[t-off] : 0;
      __syncthreads();
      sm[t] += u;
      __syncthreads();
    }
    int excl = carry + sm[t] - s;
    if (idx   < n) out[idx]   = excl;
    if (idx+1 < n) out[idx+1] = excl + v0;
    if (idx+2 < n) out[idx+2] = excl + v0+v1;
    if (idx+3 < n) out[idx+3] = excl + v0+v1+v2;
    carry += sm[1023];
    __syncthreads();
  }
  if (t == 0) out[n] = carry;
}
__global__ void k_fill_direct(const int* __restrict__ src, const int* __restrict__ dst, int E) {
  int* cur = wsi(OFF_DEG);
  int* col = wsi(OFF_COL);
  int e = blockIdx.x*blockDim.x + threadIdx.x;
  if (e < E) {
    int p = atomicAdd(&cur[dst[e]], 1);
    col[p] = src[e];
  }
}
__global__ void k_fill_bidir(const int* __restrict__ edge, int E) {
  int* cur = wsi(OFF_DEG);
  int* col = wsi(OFF_COL);
  int e = blockIdx.x*blockDim.x + threadIdx.x;
  if (e < E) {
    int u = edge[2*e], v = edge[2*e+1];
    int p = atomicAdd(&cur[v], 1); col[p] = u;
    int q = atomicAdd(&cur[u], 1); col[q] = v;
  }
}

// ---------------- propagation dim-3 (f32) ----------------
__global__ void k_spmm3(const float* __restrict__ Xext, unsigned long long Xoff,
                        unsigned long long Yoff, int n) {
  const float* X = Xext ? Xext : wsf(Xoff);
  float* Y = wsf(Yoff);
  const int* rowptr = wsi(OFF_RP);
  const int* col = wsi(OFF_COL);
  const float* nrm = wsf(OFF_NRM);
  int row = blockIdx.x*blockDim.x + threadIdx.x;
  if (row >= n) return;
  int s = rowptr[row], e = rowptr[row+1];
  float a0=0.f, a1=0.f, a2=0.f;
  for (int i = s; i < e; ++i) {
    int c = col[i]; float v = nrm[c];
    a0 = fmaf(v, X[c*3+0], a0);
    a1 = fmaf(v, X[c*3+1], a1);
    a2 = fmaf(v, X[c*3+2], a2);
  }
  float nm = nrm[row];
  Y[row*3+0] = a0*nm; Y[row*3+1] = a1*nm; Y[row*3+2] = a2*nm;
}

// ---------------- fp16 SpMM, half8 (16B) per lane, 24 lanes/row ----------------
__global__ __launch_bounds__(192) void k_spmm8(unsigned long long Xoff,
                                               unsigned long long Yoff, int n) {
  int gid = blockIdx.x*192 + threadIdx.x;
  if (gid >= n*24) return;
  int row = gid / 24, f8 = gid - row*24;
  const half8* __restrict__ X8 = (const half8*)wsh(Xoff);
  half8* __restrict__ Y8 = (half8*)wsh(Yoff);
  const int* rowptr = wsi(OFF_RP);
  const int* col = wsi(OFF_COL);
  const float* nrm = wsf(OFF_NRM);
  int s = rowptr[row], e = rowptr[row+1];
  float acc[8];
  #pragma unroll
  for (int j = 0; j < 8; ++j) acc[j] = 0.f;
  for (int i = s; i < e; ++i) {
    int c = col[i];
    float w = nrm[c];
    half8 v = X8[(size_t)c*24 + f8];
    #pragma unroll
    for (int j = 0; j < 8; ++j) acc[j] = fmaf(w, (float)v[j], acc[j]);
  }
  float nm = nrm[row];
  half8 r;
  #pragma unroll
  for (int j = 0; j < 8; ++j) r[j] = (_Float16)(acc[j]*nm);
  Y8[(size_t)row*24 + f8] = r;
}

// ---------------- first layer: [x|x1|x2](n,9)@Wf + b, relu -> H fp16 ----------------
__global__ void k_gemm_first(const float* __restrict__ xext, unsigned long long xOff,
                             const float* __restrict__ W, const float* __restrict__ b, int n) {
  const float* x  = xext ? xext : wsf(xOff);
  const float* x1 = wsf(OFF_X1F);
  const float* x2 = wsf(OFF_X2F);
  __half* H = wsh(OFF_HH);
  int idx = blockIdx.x*blockDim.x + threadIdx.x;
  if (idx >= n*HF) return;
  int row = idx / HF, c = idx - row*HF;
  float acc = b[c];
  #pragma unroll
  for (int k = 0; k < 3; ++k) acc = fmaf(x [row*3+k], W[(0+k)*HF + c], acc);
  #pragma unroll
  for (int k = 0; k < 3; ++k) acc = fmaf(x1[row*3+k], W[(3+k)*HF + c], acc);
  #pragma unroll
  for (int k = 0; k < 3; ++k) acc = fmaf(x2[row*3+k], W[(6+k)*HF + c], acc);
  H[idx] = __float2half(fmaxf(acc, 0.f));
}

// ---------------- W prep: Wt[it][col][k] = fp16(Wm[stage it][k][col]) ----------------
__global__ void k_wprep(const float* __restrict__ Wm, int s) {
  int idx = blockIdx.x*blockDim.x + threadIdx.x;
  if (idx >= 12*576*HF) return;
  int it = idx / (576*HF);
  int rem = idx - it*576*HF;
  int k = rem / HF;
  int c = rem - k*HF;
  wsh(OFF_WT)[(size_t)it*HF*576 + (size_t)c*576 + k] =
      __float2half(Wm[((size_t)(s*12+it)*576 + k)*HF + c]);
}

// ---------------- MFMA mid layer with LDS-staged B ----------------
// H = f(H@W0 + T1@W1 + T2@W2 + b), block = 64 rows x 192 cols, 4 waves
#define BPAD 104   // halves per LDS row (16B-aligned stride, 208 B)
__global__ __launch_bounds__(256) void k_mfma_mid(
    const float* __restrict__ b, int it, int n, int residual)
{
  __half* __restrict__ H = wsh(OFF_HH);
  const __half* __restrict__ T1 = wsh(OFF_T1H);
  const __half* __restrict__ T2 = wsh(OFF_T2H);
  const __half* __restrict__ Wt = wsh(OFF_WT) + (size_t)it*HF*576;
  __shared__ _Float16 Bs[192*BPAD];   // 39,936 B
  int t = threadIdx.x;
  int w = t >> 6;
  int l = t & 63;
  int lr = l & 15;   // A row / B col / D col
  int lg = l >> 4;   // k-group
  int row0 = blockIdx.x*64 + w*16;

  f32x4 acc[12];
  #pragma unroll
  for (int i = 0; i < 12; ++i) acc[i] = (f32x4){0.f,0.f,0.f,0.f};

  const __half* Xp[3] = { H, T1, T2 };
  for (int p = 0; p < 3; ++p) {
    const __half* X = Xp[p];
    for (int kh = 0; kh < 2; ++kh) {
      __syncthreads();
      // stage 192 cols x 96 k of Wt into LDS (coalesced half8)
      for (int i = t; i < 192*12; i += 256) {
        int c  = i / 12;
        int k8 = i - c*12;
        *(half8*)&Bs[c*BPAD + k8*8] =
            *(const half8*)&Wt[(size_t)c*576 + p*HF + kh*96 + k8*8];
      }
      __syncthreads();
      #pragma unroll
      for (int k0 = 0; k0 < 96; k0 += 32) {
        half8 a = *(const half8*)&X[(size_t)(row0 + lr)*HF + kh*96 + k0 + lg*8];
        #pragma unroll
        for (int tl = 0; tl < 12; ++tl) {
          half8 bb = *(const half8*)&Bs[(tl*16 + lr)*BPAD + k0 + lg*8];
          acc[tl] = __builtin_amdgcn_mfma_f32_16x16x32_f16(a, bb, acc[tl], 0, 0, 0);
        }
      }
    }
  }

  #pragma unroll
  for (int tl = 0; tl < 12; ++tl) {
    int c = tl*16 + lr;
    float bias = b[c];
    #pragma unroll
    for (int j = 0; j < 4; ++j) {
      int row = row0 + lg*4 + j;
      if (row < n) {
        size_t o = (size_t)row*HF + c;
        float cur = fmaxf(acc[tl][j] + bias, 0.f);
        float h = cur;
        if (residual) h = 0.5f*(__half2float(H[o]) + cur);
        H[o] = __float2half(h);
      }
    }
  }
}

// ---------------- last layer (linear reads), f32 out + optional f32 shadow ----------------
__global__ void k_last_lin(const float* __restrict__ W, const float* __restrict__ b,
                           float* __restrict__ outb, unsigned long long outfOff,
                           int hasOutf, int n) {
  int row = blockIdx.x*blockDim.x + threadIdx.x;
  if (row >= n) return;
  const __half* H  = wsh(OFF_HH);
  const __half* T1 = wsh(OFF_T1H);
  const __half* T2 = wsh(OFF_T2H);
  float a0 = b[0], a1 = b[1], a2 = b[2];
  const __half* x = &H[(size_t)row*HF];
  for (int k = 0; k < HF; ++k) {
    float v = __half2float(x[k]); const float* w = &W[k*3];
    a0 = fmaf(v, w[0], a0); a1 = fmaf(v, w[1], a1); a2 = fmaf(v, w[2], a2);
  }
  x = &T1[(size_t)row*HF];
  for (int k = 0; k < HF; ++k) {
    float v = __half2float(x[k]); const float* w = &W[(HF+k)*3];
    a0 = fmaf(v, w[0], a0); a1 = fmaf(v, w[1], a1); a2 = fmaf(v, w[2], a2);
  }
  x = &T2[(size_t)row*HF];
  for (int k = 0; k < HF; ++k) {
    float v = __half2float(x[k]); const float* w = &W[(2*HF+k)*3];
    a0 = fmaf(v, w[0], a0); a1 = fmaf(v, w[1], a1); a2 = fmaf(v, w[2], a2);
  }
  outb[row*3+0] = a0;
  outb[row*3+1] = a1;
  outb[row*3+2] = a2;
  if (hasOutf) {
    float* outf = wsf(outfOff);
    outf[row*3+0] = a0; outf[row*3+1] = a1; outf[row*3+2] = a2;
  }
}

// ---------------- unpool: f32 shadow in -> f32 shadow out + f32 out ----------------
__global__ void k_unpool(unsigned long long srcOff, const int* __restrict__ pidx,
                         unsigned long long dstfOff, float* __restrict__ dstb,
                         int n, int P) {
  const float* src = wsf(srcOff);
  float* dstf = wsf(dstfOff);
  int i = blockIdx.x*blockDim.x + threadIdx.x;
  if (i >= n + P) return;
  float v0, v1, v2;
  if (i < n) {
    v0 = src[i*3+0]; v1 = src[i*3+1]; v2 = src[i*3+2];
  } else {
    int a = pidx[(i-n)*2], c = pidx[(i-n)*2+1];
    v0 = 0.5f*(src[a*3+0] + src[c*3+0]);
    v1 = 0.5f*(src[a*3+1] + src[c*3+1]);
    v2 = 0.5f*(src[a*3+2] + src[c*3+2]);
  }
  dstf[i*3+0] = v0; dstf[i*3+1] = v1; dstf[i*3+2] = v2;
  dstb[i*3+0] = v0;
  dstb[i*3+1] = v1;
  dstb[i*3+2] = v2;
}

extern "C" void kernel_launch(void* const* d_in, const int* in_sizes, int n_in,
                              void* d_out, int out_size, void* d_ws, size_t ws_size,
                              hipStream_t stream) {
  (void)in_sizes; (void)n_in; (void)out_size; (void)d_ws; (void)ws_size;
  const float* features = (const float*)d_in[0];
  const int*  src0  = (const int*)d_in[1];
  const int*  dst0  = (const int*)d_in[2];
  const int*  pool0 = (const int*)d_in[3];
  const int*  edge0 = (const int*)d_in[4];
  const int*  pool1 = (const int*)d_in[5];
  const int*  edge1 = (const int*)d_in[6];
  const float* Wf = (const float*)d_in[7];
  const float* bfp = (const float*)d_in[8];
  const float* Wm = (const float*)d_in[9];
  const float* bm = (const float*)d_in[10];
  const float* Wl = (const float*)d_in[11];
  const float* bl = (const float*)d_in[12];
  float* out = (float*)d_out;

  auto csr = [&](int n, const int* srcD, const int* dstD, int Edir,
                 const int* edgeB, int Eund) {
    k_zero<<<divup(n,256),256,0,stream>>>(OFF_DEG, n);
    if (srcD) k_count_direct<<<divup(Edir,256),256,0,stream>>>(dstD, Edir);
    else      k_count_bidir <<<divup(Eund,256),256,0,stream>>>(edgeB, Eund);
    k_norm<<<divup(n,256),256,0,stream>>>(n);
    k_exscan<<<1,1024,0,stream>>>(n);
    k_copyi<<<divup(n,256),256,0,stream>>>(OFF_RP, OFF_DEG, n);
    if (srcD) k_fill_direct<<<divup(Edir,256),256,0,stream>>>(srcD, dstD, Edir);
    else      k_fill_bidir <<<divup(Eund,256),256,0,stream>>>(edgeB, Eund);
  };

  // unified fp16+MFMA stage
  auto stage_u = [&](const float* xext, unsigned long long xOff, int n,
                     const int* srcD, const int* dstD, int Edir,
                     const int* edgeB, int Eund,
                     int s, float* outb, unsigned long long outfOff, int hasOutf) {
    csr(n, srcD, dstD, Edir, edgeB, Eund);
    k_wprep<<<divup(12*576*HF,256),256,0,stream>>>(Wm, s);
    k_spmm3<<<divup(n,256),256,0,stream>>>(xext, xOff, OFF_X1F, n);
    k_spmm3<<<divup(n,256),256,0,stream>>>(nullptr, OFF_X1F, OFF_X2F, n);
    k_gemm_first<<<divup(n*HF,256),256,0,stream>>>(xext, xOff,
        Wf + (size_t)s*9*HF, bfp + s*HF, n);
    int gsp = divup(n*24,192);
    for (int it = 0; it < 12; ++it) {
      k_spmm8<<<gsp,192,0,stream>>>(OFF_HH,  OFF_T1H, n);
      k_spmm8<<<gsp,192,0,stream>>>(OFF_T1H, OFF_T2H, n);
      k_mfma_mid<<<divup(n,64),256,0,stream>>>(bm + (s*12+it)*HF, it, n,
          ((it+1)%2==0) ? 1 : 0);
    }
    k_spmm8<<<gsp,192,0,stream>>>(OFF_HH,  OFF_T1H, n);
    k_spmm8<<<gsp,192,0,stream>>>(OFF_T1H, OFF_T2H, n);
    k_last_lin<<<divup(n,256),256,0,stream>>>(Wl + (size_t)s*576*3, bl + s*3,
        outb, outfOff, hasOutf, n);
  };

  // stage 1: n=10000, direct edges
  stage_u(features, 0ull, 10000, src0, dst0, 60000, nullptr, 0,
          0, out + 0, OFF_O1F, 1);
  k_unpool<<<divup(40000,256),256,0,stream>>>(OFF_O1F, pool0, OFF_U1F, out + 630000, 10000, 30000);
  // stage 2: n=40000, bidir edge0
  stage_u(nullptr, OFF_U1F, 40000, nullptr, nullptr, 0, edge0, 120000,
          1, out + 30000, OFF_O2F, 1);
  k_unpool<<<divup(160000,256),256,0,stream>>>(OFF_O2F, pool1, OFF_U2F, out + 750000, 40000, 120000);
  // stage 3: n=160000, bidir edge1
  stage_u(nullptr, OFF_U2F, 160000, nullptr, nullptr, 0, edge1, 480000,
          2, out + 150000, OFF_O1F, 0);
}